// Round 4
// baseline (9619.912 us; speedup 1.0000x reference)
//
#include <hip/hip_runtime.h>
#include <hip/hip_bf16.h>
#include <cstdint>
#include <cstddef>

#define H 128

using f32x4v = __attribute__((ext_vector_type(4))) float;
using bf8 = __attribute__((ext_vector_type(8))) short;

__device__ __forceinline__ short f2bf(float f) {
  unsigned u = __float_as_uint(f);
  u = (u + 0x7fffu + ((u >> 16) & 1u)) >> 16;
  return (short)u;
}
__device__ __forceinline__ float bf2f(short h) {
  return __uint_as_float(((unsigned)(unsigned short)h) << 16);
}
__device__ __forceinline__ void splitf(float f, short& h, short& l) {
  h = f2bf(f);
  l = f2bf(f - bf2f(h));
}
__device__ __forceinline__ f32x4v mfma16(bf8 a, bf8 b, f32x4v c) {
  return __builtin_amdgcn_mfma_f32_16x16x32_bf16(a, b, c, 0, 0, 0);
}

// load 16-row a-frags (hi/lo) for rows arow (per-lane), cols = full 128
__device__ __forceinline__ void load_afrags(const float* __restrict__ Ap, bool av,
    float sc, bf8* ah, bf8* al_) {
#pragma unroll
  for (int ks = 0; ks < 4; ++ks) {
    float v[8];
    if (av) {
      f32x4v p0 = *(const f32x4v*)(Ap + ks * 32);
      f32x4v p1 = *(const f32x4v*)(Ap + ks * 32 + 4);
      v[0]=p0.x*sc; v[1]=p0.y*sc; v[2]=p0.z*sc; v[3]=p0.w*sc;
      v[4]=p1.x*sc; v[5]=p1.y*sc; v[6]=p1.z*sc; v[7]=p1.w*sc;
    } else {
#pragma unroll
      for (int j = 0; j < 8; ++j) v[j] = 0.f;
    }
#pragma unroll
    for (int j = 0; j < 8; ++j) { short hh, ll; splitf(v[j], hh, ll); ah[ks][j]=hh; al_[ks][j]=ll; }
  }
}

// ---------------- weight packing into MFMA b-frag layout ----------------

__global__ __launch_bounds__(256) void pack_w_k(const float* __restrict__ W,
    short* __restrict__ hi, short* __restrict__ lo, int K, int N) {
  int total = K * N;
  int t = blockIdx.x * 256 + threadIdx.x;
  int layer = blockIdx.y;
  if (t >= total) return;
  int k = t / N, n = t - k * N;
  float f = W[(size_t)layer * total + t];
  short h, l; splitf(f, h, l);
  int nt = n >> 4, ks = k >> 5, kk = k & 31;
  int lane = (n & 15) | (((kk >> 3) & 3) << 4);
  size_t idx = (size_t)layer * total + ((size_t)(nt * (K >> 5) + ks) << 9) + lane * 8 + (kk & 7);
  hi[idx] = h; lo[idx] = l;
}

// ---------------- embedding / init ----------------

__global__ __launch_bounds__(256) void atom_encode_k(const int* __restrict__ nf,
    const float* __restrict__ emb, float* __restrict__ x, float* __restrict__ abuf, int N) {
  long long t = (long long)blockIdx.x * 256 + threadIdx.x;
  if (t >= (long long)N * H) return;
  int n = (int)(t >> 7), h = (int)(t & 127);
  const int* row = nf + (size_t)n * 9;
  float s = 0.f;
#pragma unroll
  for (int f = 0; f < 9; ++f) s += emb[((size_t)f * 100 + row[f]) * H + h];
  x[t] = s;
  abuf[t] = s;
}

__global__ __launch_bounds__(256) void rg_init_k(const int* __restrict__ feat,
    const float* __restrict__ emb, float* __restrict__ rg, int NRG) {
  long long t = (long long)blockIdx.x * 256 + threadIdx.x;
  if (t >= (long long)NRG * H) return;
  int n = (int)(t >> 7), h = (int)(t & 127);
  rg[t] = emb[(size_t)feat[n] * H + h];
}

// ---------------- edge message + scatter ----------------

__global__ __launch_bounds__(256) void edge_msg_k(const int* __restrict__ ei,
    const int* __restrict__ ef, const float* __restrict__ bemb,
    const float* __restrict__ x, float* __restrict__ abuf, int E) {
  long long t = (long long)blockIdx.x * 256 + threadIdx.x;
  if (t >= (long long)E * H) return;
  int e = (int)(t >> 7), h = (int)(t & 127);
  int src = ei[e], dst = ei[(size_t)E + e];
  const int* f = ef + (size_t)e * 3;
  float v = bemb[(size_t)f[0] * H + h]
          + bemb[((size_t)100 + f[1]) * H + h]
          + bemb[((size_t)200 + f[2]) * H + h];
  float m = fmaxf(x[(size_t)src * H + h] + v, 0.f);
  atomicAdd(&abuf[(size_t)dst * H + h], m);
}

__global__ __launch_bounds__(256) void scatter_add_k(const int* __restrict__ sidx,
    const int* __restrict__ didx, const float* __restrict__ src,
    float* __restrict__ dst, int M) {
  long long t = (long long)blockIdx.x * 256 + threadIdx.x;
  if (t >= (long long)M * H) return;
  int m = (int)(t >> 7), h = (int)(t & 127);
  int sr = sidx ? sidx[m] : m;
  atomicAdd(&dst[(size_t)didx[m] * H + h], src[(size_t)sr * H + h]);
}

// ---------------- counts ----------------

__global__ __launch_bounds__(256) void count_k(const int* __restrict__ idx,
    float* __restrict__ cnt, int n) {
  int t = blockIdx.x * 256 + threadIdx.x;
  if (t < n) atomicAdd(&cnt[idx[t]], 1.0f);
}

__global__ __launch_bounds__(256) void inv_k(float* v, int n) {
  int t = blockIdx.x * 256 + threadIdx.x;
  if (t < n) v[t] = 1.0f / fmaxf(v[t], 1.0f);
}

// ---------------- batchnorm helpers ----------------

__global__ void bn_final_k(const float* __restrict__ ssum, const float* __restrict__ ssq,
    float* __restrict__ mu, float* __restrict__ rsig, int C, float invM) {
  int c = threadIdx.x + blockIdx.x * blockDim.x;
  if (c < C) {
    float m = ssum[c] * invM;
    float v = ssq[c] * invM - m * m;
    mu[c] = m;
    rsig[c] = rsqrtf(v + 1e-5f);
  }
}

__global__ __launch_bounds__(256) void bn_apply_relu_k(const float* __restrict__ X,
    const float* __restrict__ mu, const float* __restrict__ rsig,
    float* __restrict__ Out, int M) {
  long long t = (long long)blockIdx.x * 256 + threadIdx.x;
  if (t >= (long long)M * 32) return;
  int c4 = ((int)(t & 31)) * 4;
  float4 v = ((const float4*)X)[t];
  float4 m4 = *(const float4*)&mu[c4];
  float4 r4 = *(const float4*)&rsig[c4];
  v.x = fmaxf((v.x - m4.x) * r4.x, 0.f);
  v.y = fmaxf((v.y - m4.y) * r4.y, 0.f);
  v.z = fmaxf((v.z - m4.z) * r4.z, 0.f);
  v.w = fmaxf((v.w - m4.w) * r4.w, 0.f);
  ((float4*)Out)[t] = v;
}

// ---------------- MFMA MLP stats: column sum/sumsq of A[M,128] @ W1[128,256] ----------------

__global__ __launch_bounds__(256, 2) void mlp_stats_mfma_k(
    const float* __restrict__ A, const short* __restrict__ w1h, const short* __restrict__ w1l,
    float* __restrict__ ssum, float* __restrict__ ssq, int M, int ntiles) {
  __shared__ float sRed[256], qRed[256];
  int tid = threadIdx.x;
  sRed[tid] = 0.f; qRed[tid] = 0.f;
  __syncthreads();
  int w = tid >> 6, l = tid & 63, l15 = l & 15, lg = l >> 4;
  float sAcc[16], qAcc[16];
#pragma unroll
  for (int nt = 0; nt < 16; ++nt) { sAcc[nt] = 0.f; qAcc[nt] = 0.f; }
  for (int tb = blockIdx.x; tb < ntiles; tb += gridDim.x) {
    int arow = tb * 64 + w * 16 + l15;
    bool av = arow < M;
    bf8 ah[4], al_[4];
    load_afrags(A + (size_t)arow * 128 + lg * 8, av, 1.f, ah, al_);
#pragma unroll
    for (int nt = 0; nt < 16; ++nt) {
      f32x4v c = {0.f, 0.f, 0.f, 0.f};
      const short* bph = w1h + nt * 2048 + l * 8;
      const short* bpl = w1l + nt * 2048 + l * 8;
#pragma unroll
      for (int ks = 0; ks < 4; ++ks) {
        bf8 bh = *(const bf8*)(bph + ks * 512);
        bf8 bl = *(const bf8*)(bpl + ks * 512);
        c = mfma16(al_[ks], bh, c);
        c = mfma16(ah[ks], bl, c);
        c = mfma16(ah[ks], bh, c);
      }
      sAcc[nt] += c[0] + c[1] + c[2] + c[3];
      qAcc[nt] += c[0]*c[0] + c[1]*c[1] + c[2]*c[2] + c[3]*c[3];
    }
  }
#pragma unroll
  for (int nt = 0; nt < 16; ++nt) {
    float s = sAcc[nt], q = qAcc[nt];
    s += __shfl_xor(s, 16); s += __shfl_xor(s, 32);
    q += __shfl_xor(q, 16); q += __shfl_xor(q, 32);
    if (l < 16) { atomicAdd(&sRed[nt * 16 + l], s); atomicAdd(&qRed[nt * 16 + l], q); }
  }
  __syncthreads();
  atomicAdd(&ssum[tid], sRed[tid]);
  atomicAdd(&ssq[tid], qRed[tid]);
}

// ---------------- MFMA fused MLP: A <- relu(BN1(A@W1))@W2 in-place, + BN2 col stats ----------------
// Register-disciplined: stage1 streams one c-frag per nt to LDS; stage2 hoists the
// 16 LDS a-frags once per tile and streams one output c-frag per nt.

__global__ __launch_bounds__(256, 2) void mlp_fused_mfma_k(
    float* __restrict__ A, const short* __restrict__ w1h, const short* __restrict__ w1l,
    const short* __restrict__ w2h, const short* __restrict__ w2l,
    const float* __restrict__ mu, const float* __restrict__ rsig,
    float* __restrict__ ssum, float* __restrict__ ssq, int M, int ntiles) {
  __shared__ __align__(16) short Th[4][4096];  // per-wave h1 (hi), stage-2 a-frag layout
  __shared__ __align__(16) short Tl[4][4096];
  __shared__ float sRed[128], qRed[128];
  int tid = threadIdx.x;
  if (tid < 128) { sRed[tid] = 0.f; qRed[tid] = 0.f; }
  __syncthreads();
  int w = tid >> 6, l = tid & 63, l15 = l & 15, lg = l >> 4;
  float sAcc[8], qAcc[8];
#pragma unroll
  for (int nt = 0; nt < 8; ++nt) { sAcc[nt] = 0.f; qAcc[nt] = 0.f; }
  for (int tb = blockIdx.x; tb < ntiles; tb += gridDim.x) {
    int arow = tb * 64 + w * 16 + l15;
    bool av = arow < M;
    {
      bf8 ah[4], al_[4];
      load_afrags(A + (size_t)arow * 128 + lg * 8, av, 1.f, ah, al_);
      // ---- stage 1: per-nt stream to LDS
#pragma unroll
      for (int nt = 0; nt < 16; ++nt) {
        f32x4v c = {0.f, 0.f, 0.f, 0.f};
        const short* bph = w1h + nt * 2048 + l * 8;
        const short* bpl = w1l + nt * 2048 + l * 8;
#pragma unroll
        for (int ks = 0; ks < 4; ++ks) {
          bf8 bh = *(const bf8*)(bph + ks * 512);
          bf8 bl = *(const bf8*)(bpl + ks * 512);
          c = mfma16(al_[ks], bh, c);
          c = mfma16(ah[ks], bl, c);
          c = mfma16(ah[ks], bh, c);
        }
        int cc = nt * 16 + l15;
        float mm = mu[cc], rs = rsig[cc];
        int qsel = ((cc >> 3) & 3) << 4;
        int idx0 = ((cc >> 5) << 9) + (cc & 7);
#pragma unroll
        for (int r = 0; r < 4; ++r) {
          float t = fmaxf((c[r] - mm) * rs, 0.f);
          short hh, ll; splitf(t, hh, ll);
          int idx = idx0 + ((lg * 4 + r) | qsel) * 8;
          Th[w][idx] = hh;
          Tl[w][idx] = ll;
        }
      }
    }
    // ---- stage 2: hoist LDS a-frags once, stream per-nt output
    bf8 a2h[8], a2l[8];
#pragma unroll
    for (int ks = 0; ks < 8; ++ks) {
      a2h[ks] = *(const bf8*)&Th[w][ks * 512 + l * 8];
      a2l[ks] = *(const bf8*)&Tl[w][ks * 512 + l * 8];
    }
    int base = tb * 64 + w * 16;
#pragma unroll
    for (int nt = 0; nt < 8; ++nt) {
      f32x4v c = {0.f, 0.f, 0.f, 0.f};
      const short* b2h = w2h + nt * 4096 + l * 8;
      const short* b2l = w2l + nt * 4096 + l * 8;
#pragma unroll
      for (int ks = 0; ks < 8; ++ks) {
        bf8 bh = *(const bf8*)(b2h + ks * 512);
        bf8 bl = *(const bf8*)(b2l + ks * 512);
        c = mfma16(a2l[ks], bh, c);
        c = mfma16(a2h[ks], bl, c);
        c = mfma16(a2h[ks], bh, c);
      }
      int cc = nt * 16 + l15;
#pragma unroll
      for (int r = 0; r < 4; ++r) {
        int gr = base + lg * 4 + r;
        if (gr < M) {
          float vv = c[r];
          A[(size_t)gr * 128 + cc] = vv;
          sAcc[nt] += vv;
          qAcc[nt] = fmaf(vv, vv, qAcc[nt]);
        }
      }
    }
  }
#pragma unroll
  for (int nt = 0; nt < 8; ++nt) {
    float s = sAcc[nt], q = qAcc[nt];
    s += __shfl_xor(s, 16); s += __shfl_xor(s, 32);
    q += __shfl_xor(q, 16); q += __shfl_xor(q, 32);
    if (l < 16) { atomicAdd(&sRed[nt * 16 + l], s); atomicAdd(&qRed[nt * 16 + l], q); }
  }
  __syncthreads();
  if (tid < 128) { atomicAdd(&ssum[tid], sRed[tid]); atomicAdd(&ssq[tid], qRed[tid]); }
}

// ---------------- MFMA 128x128 GEMM: Out=Out+relu((A*aux)@W); Out2=Out (W in LDS) ----------------

__global__ __launch_bounds__(256, 2) void gemm128_mfma_k(
    const float* __restrict__ A0, const float* __restrict__ AUX,
    const short* __restrict__ wh, const short* __restrict__ wl,
    float* __restrict__ Out, float* __restrict__ Out2, int M, int ntiles) {
  __shared__ __align__(16) short Wh[16384], Wl[16384];
  int tid = threadIdx.x;
  for (int i = tid; i < 2048; i += 256) {
    ((f32x4v*)Wh)[i] = ((const f32x4v*)wh)[i];
    ((f32x4v*)Wl)[i] = ((const f32x4v*)wl)[i];
  }
  __syncthreads();
  int w = tid >> 6, l = tid & 63, l15 = l & 15, lg = l >> 4;
  for (int tb = blockIdx.x; tb < ntiles; tb += gridDim.x) {
    int arow = tb * 64 + w * 16 + l15;
    bool av = arow < M;
    float sc = av ? AUX[arow] : 0.f;
    bf8 ah[4], al_[4];
    load_afrags(A0 + (size_t)arow * 128 + lg * 8, av, sc, ah, al_);
    int base = tb * 64 + w * 16;
#pragma unroll
    for (int nt = 0; nt < 8; ++nt) {
      f32x4v c = {0.f, 0.f, 0.f, 0.f};
#pragma unroll
      for (int ks = 0; ks < 4; ++ks) {
        bf8 bh = *(const bf8*)&Wh[(nt * 4 + ks) * 512 + l * 8];
        bf8 bl = *(const bf8*)&Wl[(nt * 4 + ks) * 512 + l * 8];
        c = mfma16(al_[ks], bh, c);
        c = mfma16(ah[ks], bl, c);
        c = mfma16(ah[ks], bh, c);
      }
#pragma unroll
      for (int r = 0; r < 4; ++r) {
        int gr = base + lg * 4 + r;
        if (gr < M) {
          size_t o = (size_t)gr * 128 + nt * 16 + l15;
          float t = Out[o] + fmaxf(c[r], 0.f);
          Out[o] = t;
          Out2[o] = t;
        }
      }
    }
  }
}

// ---------------- f32 GEMM for readout (small) ----------------
template<int PRO, int EPI>
__global__ __launch_bounds__(256) void gemm_k(
    const float* __restrict__ A0, const float* __restrict__ AUX,
    const float* __restrict__ W, float* __restrict__ Out, int M) {
  __shared__ __align__(16) float Ash[64][64];
  int tid = threadIdx.x;
  int tc = tid & 63, tr = tid >> 6;
  int row0 = blockIdx.x * 64;
  float acc[16][2];
#pragma unroll
  for (int i = 0; i < 16; ++i) { acc[i][0] = 0.f; acc[i][1] = 0.f; }
  for (int k0 = 0; k0 < 128; k0 += 64) {
#pragma unroll
    for (int it = 0; it < 4; ++it) {
      int fidx = tid + it * 256;
      int r = fidx >> 4, c4 = (fidx & 15) << 2;
      int gr = row0 + r;
      float4 v = make_float4(0.f, 0.f, 0.f, 0.f);
      if (gr < M) {
        v = *(const float4*)(A0 + (size_t)gr * 128 + k0 + c4);
        if (PRO == 2) { float s = AUX[gr]; v.x *= s; v.y *= s; v.z *= s; v.w *= s; }
      }
      *(float4*)&Ash[r][c4] = v;
    }
    __syncthreads();
    const float* Wp = W + (size_t)k0 * 128 + tc;
    for (int kk = 0; kk < 64; kk += 4) {
      float w[4][2];
#pragma unroll
      for (int kj = 0; kj < 4; ++kj)
#pragma unroll
        for (int j = 0; j < 2; ++j) w[kj][j] = Wp[(size_t)(kk + kj) * 128 + j * 64];
#pragma unroll
      for (int i = 0; i < 16; ++i) {
        float4 a = *(const float4*)&Ash[tr * 16 + i][kk];
#pragma unroll
        for (int j = 0; j < 2; ++j) {
          acc[i][j] = fmaf(a.x, w[0][j], acc[i][j]);
          acc[i][j] = fmaf(a.y, w[1][j], acc[i][j]);
          acc[i][j] = fmaf(a.z, w[2][j], acc[i][j]);
          acc[i][j] = fmaf(a.w, w[3][j], acc[i][j]);
        }
      }
    }
    __syncthreads();
  }
#pragma unroll
  for (int i = 0; i < 16; ++i) {
    int gr = row0 + tr * 16 + i;
    if (gr < M) {
#pragma unroll
      for (int j = 0; j < 2; ++j) {
        size_t o = (size_t)gr * 128 + tc + j * 64;
        float v = acc[i][j];
        if (EPI == 0) Out[o] = v;
        else Out[o] = fmaxf(Out[o] + v, 0.f);
      }
    }
  }
}

// ---------------- host ----------------

static inline int cdivll(long long a, long long b) { return (int)((a + b - 1) / b); }

extern "C" void kernel_launch(void* const* d_in, const int* in_sizes, int n_in,
                              void* d_out, int out_size, void* d_ws, size_t ws_size,
                              hipStream_t stream) {
  const int* node_feat  = (const int*)d_in[0];
  const int* edge_index = (const int*)d_in[1];
  const int* edge_feat  = (const int*)d_in[2];
  const int* batch      = (const int*)d_in[3];
  const int* map_row    = (const int*)d_in[4];
  const int* map_col    = (const int*)d_in[5];
  const int* rg_ei      = (const int*)d_in[6];
  const int* rg_feat    = (const int*)d_in[7];
  const int* tree_batch = (const int*)d_in[8];
  const float* atom_emb   = (const float*)d_in[10];
  const float* bond_emb   = (const float*)d_in[11];
  const float* rg_emb     = (const float*)d_in[12];
  const float* atom_W1    = (const float*)d_in[13];
  const float* atom_W2    = (const float*)d_in[14];
  const float* rg_W1      = (const float*)d_in[15];
  const float* rg_W2      = (const float*)d_in[16];
  const float* raw2rg_W   = (const float*)d_in[17];
  const float* rg2raw_W   = (const float*)d_in[18];
  const float* atom_lin_W = (const float*)d_in[19];
  const float* rg_lin_W   = (const float*)d_in[20];
  const float* lin_W      = (const float*)d_in[21];

  const int N   = in_sizes[0] / 9;
  const int E   = in_sizes[1] / 2;
  const int M   = in_sizes[4];
  const int NRG = in_sizes[7];
  const int ERG = in_sizes[6] / 2;
  const int G   = out_size / H;
  if (N <= 0 || G <= 0) return;

  const size_t NH = (size_t)N * H, RH = (size_t)NRG * H, GH = (size_t)G * H;
  const size_t need = 2 * NH + RH + (size_t)NRG + (size_t)N + 2 * (size_t)G + 1024 + 500000;
  if (ws_size < need * sizeof(float)) return;

  float* ws = (float*)d_ws;
  size_t off = 0;
  auto alloc = [&](size_t n) { float* p = ws + off; off += n; return p; };
  float* x    = alloc(NH);
  float* abuf = alloc(NH);
  float* rg   = alloc(RH);
  float* cnt_col   = alloc((size_t)NRG);
  float* cnt_row   = alloc((size_t)N);
  float* cnt_batch = alloc((size_t)G);
  float* cnt_tree  = alloc((size_t)G);
  float* ssum = alloc(256);
  float* ssq  = alloc(256);
  float* mu   = alloc(256);
  float* rsig = alloc(256);
  off = (off + 3) & ~(size_t)3;
  short* sp = (short*)(ws + off);
  size_t soff = 0;
  auto salloc = [&](size_t n) { short* p = sp + soff; soff += n; return p; };
  short* paW1h = salloc(3 * 32768); short* paW1l = salloc(3 * 32768);
  short* paW2h = salloc(3 * 32768); short* paW2l = salloc(3 * 32768);
  short* prW1h = salloc(3 * 32768); short* prW1l = salloc(3 * 32768);
  short* prW2h = salloc(3 * 32768); short* prW2l = salloc(3 * 32768);
  short* p2gh  = salloc(3 * 16384); short* p2gl  = salloc(3 * 16384);
  short* pg2h  = salloc(3 * 16384); short* pg2l  = salloc(3 * 16384);

  const int ta = (N + 63) >> 6, trg = (NRG + 63) >> 6;
  const int ga = ta < 512 ? ta : 512, grg = trg < 512 ? trg : 512;

  // ---- pack weights ----
  pack_w_k<<<dim3(128, 3), 256, 0, stream>>>(atom_W1, paW1h, paW1l, 128, 256);
  pack_w_k<<<dim3(128, 3), 256, 0, stream>>>(atom_W2, paW2h, paW2l, 256, 128);
  pack_w_k<<<dim3(128, 3), 256, 0, stream>>>(rg_W1, prW1h, prW1l, 128, 256);
  pack_w_k<<<dim3(128, 3), 256, 0, stream>>>(rg_W2, prW2h, prW2l, 256, 128);
  pack_w_k<<<dim3(64, 3), 256, 0, stream>>>(raw2rg_W, p2gh, p2gl, 128, 128);
  pack_w_k<<<dim3(64, 3), 256, 0, stream>>>(rg2raw_W, pg2h, pg2l, 128, 128);

  // ---- counts ----
  hipMemsetAsync(cnt_col, 0, (size_t)(NRG + N + 2 * G) * 4, stream);
  count_k<<<cdivll(M, 256), 256, 0, stream>>>(map_col, cnt_col, M);
  count_k<<<cdivll(M, 256), 256, 0, stream>>>(map_row, cnt_row, M);
  count_k<<<cdivll(N, 256), 256, 0, stream>>>(batch, cnt_batch, N);
  count_k<<<cdivll(NRG, 256), 256, 0, stream>>>(tree_batch, cnt_tree, NRG);
  inv_k<<<cdivll(NRG + N + 2 * G, 256), 256, 0, stream>>>(cnt_col, NRG + N + 2 * G);

  // ---- encoders ----
  atom_encode_k<<<cdivll(NH, 256), 256, 0, stream>>>(node_feat, atom_emb, x, abuf, N);
  rg_init_k<<<cdivll(RH, 256), 256, 0, stream>>>(rg_feat, rg_emb, rg, NRG);

  for (int i = 0; i < 3; ++i) {
    // --- GINE: abuf = x + agg ---
    edge_msg_k<<<cdivll((long long)E * H, 256), 256, 0, stream>>>(
        edge_index, edge_feat, bond_emb + (size_t)i * 3 * 100 * H, x, abuf, E);
    // --- atom MLP (MFMA) ---
    hipMemsetAsync(ssum, 0, 512 * 4, stream);
    mlp_stats_mfma_k<<<ga, 256, 0, stream>>>(abuf, paW1h + i * 32768, paW1l + i * 32768, ssum, ssq, N, ta);
    bn_final_k<<<1, 256, 0, stream>>>(ssum, ssq, mu, rsig, 256, 1.0f / N);
    hipMemsetAsync(ssum, 0, 512 * 4, stream);
    mlp_fused_mfma_k<<<ga, 256, 0, stream>>>(abuf, paW1h + i * 32768, paW1l + i * 32768,
        paW2h + i * 32768, paW2l + i * 32768, mu, rsig, ssum, ssq, N, ta);
    bn_final_k<<<1, 256, 0, stream>>>(ssum, ssq, mu, rsig, 128, 1.0f / N);
    bn_apply_relu_k<<<cdivll((long long)N * 32, 256), 256, 0, stream>>>(abuf, mu, rsig, x, N);

    // --- raw -> rg ---
    hipMemsetAsync(abuf, 0, RH * 4, stream);
    scatter_add_k<<<cdivll((long long)M * H, 256), 256, 0, stream>>>(map_row, map_col, x, abuf, M);
    gemm128_mfma_k<<<grg, 256, 0, stream>>>(abuf, cnt_col, p2gh + i * 16384, p2gl + i * 16384,
        rg, abuf, NRG, trg);

    // --- rg GIN ---
    scatter_add_k<<<cdivll((long long)ERG * H, 256), 256, 0, stream>>>(rg_ei, rg_ei + ERG, rg, abuf, ERG);
    hipMemsetAsync(ssum, 0, 512 * 4, stream);
    mlp_stats_mfma_k<<<grg, 256, 0, stream>>>(abuf, prW1h + i * 32768, prW1l + i * 32768, ssum, ssq, NRG, trg);
    bn_final_k<<<1, 256, 0, stream>>>(ssum, ssq, mu, rsig, 256, 1.0f / NRG);
    hipMemsetAsync(ssum, 0, 512 * 4, stream);
    mlp_fused_mfma_k<<<grg, 256, 0, stream>>>(abuf, prW1h + i * 32768, prW1l + i * 32768,
        prW2h + i * 32768, prW2l + i * 32768, mu, rsig, ssum, ssq, NRG, trg);
    bn_final_k<<<1, 256, 0, stream>>>(ssum, ssq, mu, rsig, 128, 1.0f / NRG);
    bn_apply_relu_k<<<cdivll((long long)NRG * 32, 256), 256, 0, stream>>>(abuf, mu, rsig, rg, NRG);

    // --- rg -> raw ---
    hipMemsetAsync(abuf, 0, NH * 4, stream);
    scatter_add_k<<<cdivll((long long)M * H, 256), 256, 0, stream>>>(map_col, map_row, rg, abuf, M);
    gemm128_mfma_k<<<ga, 256, 0, stream>>>(abuf, cnt_row, pg2h + i * 16384, pg2l + i * 16384,
        x, abuf, N, ta);
  }

  // ---- readout ----
  float* xg  = abuf;
  float* rgg = abuf + GH;
  float* P   = abuf + 2 * GH;
  hipMemsetAsync(abuf, 0, 2 * GH * 4, stream);
  scatter_add_k<<<cdivll(NH, 256), 256, 0, stream>>>(nullptr, batch, x, xg, N);
  scatter_add_k<<<cdivll(RH, 256), 256, 0, stream>>>(nullptr, tree_batch, rg, rgg, NRG);
  gemm_k<2, 0><<<cdivll(G, 64), 256, 0, stream>>>(xg, cnt_batch, atom_lin_W, P, G);
  gemm_k<2, 2><<<cdivll(G, 64), 256, 0, stream>>>(rgg, cnt_tree, rg_lin_W, P, G);
  gemm_k<0, 0><<<cdivll(G, 64), 256, 0, stream>>>(P, nullptr, lin_W, (float*)d_out, G);
}

// Round 5
// 4379.766 us; speedup vs baseline: 2.1964x; 2.1964x over previous
//
#include <hip/hip_runtime.h>
#include <hip/hip_bf16.h>
#include <cstdint>
#include <cstddef>

#define H 128

using f32x4v = __attribute__((ext_vector_type(4))) float;
using bf8 = __attribute__((ext_vector_type(8))) short;

__device__ __forceinline__ short f2bf(float f) {
  unsigned u = __float_as_uint(f);
  u = (u + 0x7fffu + ((u >> 16) & 1u)) >> 16;
  return (short)u;
}
__device__ __forceinline__ float bf2f(short h) {
  return __uint_as_float(((unsigned)(unsigned short)h) << 16);
}
__device__ __forceinline__ void splitf(float f, short& h, short& l) {
  h = f2bf(f);
  l = f2bf(f - bf2f(h));
}
__device__ __forceinline__ f32x4v mfma16(bf8 a, bf8 b, f32x4v c) {
  return __builtin_amdgcn_mfma_f32_16x16x32_bf16(a, b, c, 0, 0, 0);
}

// load a-frags (hi/lo) for one 16-row group, full K=128
__device__ __forceinline__ void load_afrags(const float* __restrict__ Ap, bool av,
    float sc, bf8* ah, bf8* al_) {
#pragma unroll
  for (int ks = 0; ks < 4; ++ks) {
    float v[8];
    if (av) {
      f32x4v p0 = *(const f32x4v*)(Ap + ks * 32);
      f32x4v p1 = *(const f32x4v*)(Ap + ks * 32 + 4);
      v[0]=p0.x*sc; v[1]=p0.y*sc; v[2]=p0.z*sc; v[3]=p0.w*sc;
      v[4]=p1.x*sc; v[5]=p1.y*sc; v[6]=p1.z*sc; v[7]=p1.w*sc;
    } else {
#pragma unroll
      for (int j = 0; j < 8; ++j) v[j] = 0.f;
    }
#pragma unroll
    for (int j = 0; j < 8; ++j) { short hh, ll; splitf(v[j], hh, ll); ah[ks][j]=hh; al_[ks][j]=ll; }
  }
}

// ---------------- weight packing into MFMA b-frag layout ----------------
// W[k][n] -> frag idx = (nt*(K/32)+ks)*512 + lane*8 + b, lane=(n&15)|((kk>>3)<<4), b=kk&7

__global__ __launch_bounds__(256) void pack_w_k(const float* __restrict__ W,
    short* __restrict__ hi, short* __restrict__ lo, int K, int N) {
  int total = K * N;
  int t = blockIdx.x * 256 + threadIdx.x;
  int layer = blockIdx.y;
  if (t >= total) return;
  int k = t / N, n = t - k * N;
  float f = W[(size_t)layer * total + t];
  short h, l; splitf(f, h, l);
  int nt = n >> 4, ks = k >> 5, kk = k & 31;
  int lane = (n & 15) | (((kk >> 3) & 3) << 4);
  size_t idx = (size_t)layer * total + ((size_t)(nt * (K >> 5) + ks) << 9) + lane * 8 + (kk & 7);
  hi[idx] = h; lo[idx] = l;
}

// ---------------- embedding / init ----------------

__global__ __launch_bounds__(256) void atom_encode_k(const int* __restrict__ nf,
    const float* __restrict__ emb, float* __restrict__ x, float* __restrict__ abuf, int N) {
  long long t = (long long)blockIdx.x * 256 + threadIdx.x;
  if (t >= (long long)N * H) return;
  int n = (int)(t >> 7), h = (int)(t & 127);
  const int* row = nf + (size_t)n * 9;
  float s = 0.f;
#pragma unroll
  for (int f = 0; f < 9; ++f) s += emb[((size_t)f * 100 + row[f]) * H + h];
  x[t] = s;
  abuf[t] = s;
}

__global__ __launch_bounds__(256) void rg_init_k(const int* __restrict__ feat,
    const float* __restrict__ emb, float* __restrict__ rg, int NRG) {
  long long t = (long long)blockIdx.x * 256 + threadIdx.x;
  if (t >= (long long)NRG * H) return;
  int n = (int)(t >> 7), h = (int)(t & 127);
  rg[t] = emb[(size_t)feat[n] * H + h];
}

// ---------------- edge message + scatter ----------------

__global__ __launch_bounds__(256) void edge_msg_k(const int* __restrict__ ei,
    const int* __restrict__ ef, const float* __restrict__ bemb,
    const float* __restrict__ x, float* __restrict__ abuf, int E) {
  long long t = (long long)blockIdx.x * 256 + threadIdx.x;
  if (t >= (long long)E * H) return;
  int e = (int)(t >> 7), h = (int)(t & 127);
  int src = ei[e], dst = ei[(size_t)E + e];
  const int* f = ef + (size_t)e * 3;
  float v = bemb[(size_t)f[0] * H + h]
          + bemb[((size_t)100 + f[1]) * H + h]
          + bemb[((size_t)200 + f[2]) * H + h];
  float m = fmaxf(x[(size_t)src * H + h] + v, 0.f);
  atomicAdd(&abuf[(size_t)dst * H + h], m);
}

__global__ __launch_bounds__(256) void scatter_add_k(const int* __restrict__ sidx,
    const int* __restrict__ didx, const float* __restrict__ src,
    float* __restrict__ dst, int M) {
  long long t = (long long)blockIdx.x * 256 + threadIdx.x;
  if (t >= (long long)M * H) return;
  int m = (int)(t >> 7), h = (int)(t & 127);
  int sr = sidx ? sidx[m] : m;
  atomicAdd(&dst[(size_t)didx[m] * H + h], src[(size_t)sr * H + h]);
}

// ---------------- counts ----------------

__global__ __launch_bounds__(256) void count_k(const int* __restrict__ idx,
    float* __restrict__ cnt, int n) {
  int t = blockIdx.x * 256 + threadIdx.x;
  if (t < n) atomicAdd(&cnt[idx[t]], 1.0f);
}

__global__ __launch_bounds__(256) void inv_k(float* v, int n) {
  int t = blockIdx.x * 256 + threadIdx.x;
  if (t < n) v[t] = 1.0f / fmaxf(v[t], 1.0f);
}

// ---------------- batchnorm helpers ----------------

__global__ void bn_final_k(const float* __restrict__ ssum, const float* __restrict__ ssq,
    float* __restrict__ mu, float* __restrict__ rsig, int C, float invM) {
  int c = threadIdx.x + blockIdx.x * blockDim.x;
  if (c < C) {
    float m = ssum[c] * invM;
    float v = ssq[c] * invM - m * m;
    mu[c] = m;
    rsig[c] = rsqrtf(v + 1e-5f);
  }
}

__global__ __launch_bounds__(256) void bn_apply_relu_k(const float* __restrict__ X,
    const float* __restrict__ mu, const float* __restrict__ rsig,
    float* __restrict__ Out, int M) {
  long long t = (long long)blockIdx.x * 256 + threadIdx.x;
  if (t >= (long long)M * 32) return;
  int c4 = ((int)(t & 31)) * 4;
  float4 v = ((const float4*)X)[t];
  float4 m4 = *(const float4*)&mu[c4];
  float4 r4 = *(const float4*)&rsig[c4];
  v.x = fmaxf((v.x - m4.x) * r4.x, 0.f);
  v.y = fmaxf((v.y - m4.y) * r4.y, 0.f);
  v.z = fmaxf((v.z - m4.z) * r4.z, 0.f);
  v.w = fmaxf((v.w - m4.w) * r4.w, 0.f);
  ((float4*)Out)[t] = v;
}

// ---------------- MFMA MLP stats: col sum/sumsq of A[M,128] @ W1[128,256] ----------------
// W1 staged in LDS in 4 chunks of 32 KB (4 nt each), barrier-fenced.

__global__ __launch_bounds__(256) void mlp_stats_mfma_k(
    const float* __restrict__ A, const short* __restrict__ w1h, const short* __restrict__ w1l,
    float* __restrict__ ssum, float* __restrict__ ssq, int M, int ntiles) {
  __shared__ __align__(16) short Wch[8192], Wcl[8192];  // 32 KB
  __shared__ float sRed[256], qRed[256];
  int tid = threadIdx.x;
  sRed[tid] = 0.f; qRed[tid] = 0.f;
  int w = tid >> 6, l = tid & 63, l15 = l & 15, lg = l >> 4;
  float sAcc[16], qAcc[16];
#pragma unroll
  for (int nt = 0; nt < 16; ++nt) { sAcc[nt] = 0.f; qAcc[nt] = 0.f; }
  for (int tb = blockIdx.x; tb < ntiles; tb += gridDim.x) {
    int arow = tb * 64 + w * 16 + l15;
    bool av = arow < M;
    bf8 ah[4], al_[4];
    load_afrags(A + (size_t)arow * 128 + lg * 8, av, 1.f, ah, al_);
    for (int ch = 0; ch < 4; ++ch) {
      __syncthreads();
      const bf8* srcH = (const bf8*)(w1h + ch * 8192);
      const bf8* srcL = (const bf8*)(w1l + ch * 8192);
      for (int it = tid; it < 1024; it += 256) {
        ((bf8*)Wch)[it] = srcH[it];
        ((bf8*)Wcl)[it] = srcL[it];
      }
      __syncthreads();
#pragma unroll
      for (int ntl = 0; ntl < 4; ++ntl) {
        f32x4v c = {0.f, 0.f, 0.f, 0.f};
#pragma unroll
        for (int ks = 0; ks < 4; ++ks) {
          bf8 bh = *(const bf8*)&Wch[(ntl * 4 + ks) * 512 + l * 8];
          bf8 bl = *(const bf8*)&Wcl[(ntl * 4 + ks) * 512 + l * 8];
          c = mfma16(al_[ks], bh, c);
          c = mfma16(ah[ks], bl, c);
          c = mfma16(ah[ks], bh, c);
        }
        int nt = ch * 4 + ntl;
        sAcc[nt] += c[0] + c[1] + c[2] + c[3];
        qAcc[nt] += c[0]*c[0] + c[1]*c[1] + c[2]*c[2] + c[3]*c[3];
      }
    }
  }
  __syncthreads();
#pragma unroll
  for (int nt = 0; nt < 16; ++nt) {
    float s = sAcc[nt], q = qAcc[nt];
    s += __shfl_xor(s, 16); s += __shfl_xor(s, 32);
    q += __shfl_xor(q, 16); q += __shfl_xor(q, 32);
    if (l < 16) { atomicAdd(&sRed[nt * 16 + l], s); atomicAdd(&qRed[nt * 16 + l], q); }
  }
  __syncthreads();
  atomicAdd(&ssum[tid], sRed[tid]);
  atomicAdd(&ssq[tid], qRed[tid]);
}

// ---------------- MFMA fused MLP: A <- relu(BN1(A@W1))@W2 in-place, + BN2 stats ----------------
// K processed in two 128-halves; h1 (post BN+relu) kept in LDS f32 [64][132];
// W1/W2 staged per 32 KB chunk with barriers (bounds register live ranges).

__global__ __launch_bounds__(256) void mlp_fused_mfma_k(
    float* __restrict__ A, const short* __restrict__ w1h, const short* __restrict__ w1l,
    const short* __restrict__ w2h, const short* __restrict__ w2l,
    const float* __restrict__ mu, const float* __restrict__ rsig,
    float* __restrict__ ssum, float* __restrict__ ssq, int M, int ntiles) {
  __shared__ __align__(16) short Wch[8192], Wcl[8192];  // 32 KB
  __shared__ __align__(16) float h1f[64][132];          // 33.8 KB
  __shared__ float sRed[128], qRed[128];
  int tid = threadIdx.x;
  if (tid < 128) { sRed[tid] = 0.f; qRed[tid] = 0.f; }
  int w = tid >> 6, l = tid & 63, l15 = l & 15, lg = l >> 4;
  float sAcc[8], qAcc[8];
#pragma unroll
  for (int nt = 0; nt < 8; ++nt) { sAcc[nt] = 0.f; qAcc[nt] = 0.f; }
  for (int tb = blockIdx.x; tb < ntiles; tb += gridDim.x) {
    int arow = tb * 64 + w * 16 + l15;
    bool av = arow < M;
    f32x4v acc[8];
#pragma unroll
    for (int nt = 0; nt < 8; ++nt) acc[nt] = (f32x4v){0.f, 0.f, 0.f, 0.f};
    for (int kh = 0; kh < 2; ++kh) {
      // ---- stage 1: compute h1 cols [kh*128, kh*128+128) into h1f
      {
        bf8 ah[4], al_[4];
        load_afrags(A + (size_t)arow * 128 + lg * 8, av, 1.f, ah, al_);
        for (int ch = 0; ch < 2; ++ch) {
          int cbase = kh * 8 + ch * 4;  // global nt base
          __syncthreads();  // prior LDS consumers done (W reuse / h1f reads)
          const bf8* srcH = (const bf8*)(w1h + cbase * 2048);
          const bf8* srcL = (const bf8*)(w1l + cbase * 2048);
          for (int it = tid; it < 1024; it += 256) {
            ((bf8*)Wch)[it] = srcH[it];
            ((bf8*)Wcl)[it] = srcL[it];
          }
          __syncthreads();
#pragma unroll
          for (int ntl = 0; ntl < 4; ++ntl) {
            f32x4v c = {0.f, 0.f, 0.f, 0.f};
#pragma unroll
            for (int ks = 0; ks < 4; ++ks) {
              bf8 bh = *(const bf8*)&Wch[(ntl * 4 + ks) * 512 + l * 8];
              bf8 bl = *(const bf8*)&Wcl[(ntl * 4 + ks) * 512 + l * 8];
              c = mfma16(al_[ks], bh, c);
              c = mfma16(ah[ks], bl, c);
              c = mfma16(ah[ks], bh, c);
            }
            int cn = cbase + ntl;
            int cc = cn * 16 + l15;
            float mm = mu[cc], rs = rsig[cc];
#pragma unroll
            for (int r = 0; r < 4; ++r) {
              float t = fmaxf((c[r] - mm) * rs, 0.f);
              h1f[w * 16 + lg * 4 + r][(cn & 7) * 16 + l15] = t;
            }
          }
        }
      }
      __syncthreads();  // h1f half complete
      // ---- build stage-2 a-frags from h1f
      bf8 a2h[4], a2l[4];
#pragma unroll
      for (int ks2 = 0; ks2 < 4; ++ks2) {
        const float* hp = &h1f[w * 16 + l15][ks2 * 32 + lg * 8];
#pragma unroll
        for (int j = 0; j < 8; ++j) {
          short hh, ll; splitf(hp[j], hh, ll);
          a2h[ks2][j] = hh; a2l[ks2][j] = ll;
        }
      }
      // ---- stage 2 partial: acc += h1_half @ W2[K-half]
      for (int c2 = 0; c2 < 2; ++c2) {
        __syncthreads();  // previous W chunk fully consumed
        for (int it = tid; it < 1024; it += 256) {
          int e = it * 8;
          int ntl = e >> 11, rem = e & 2047;
          int ks2 = rem >> 9, s = rem & 511;
          int src = ((c2 * 4 + ntl) * 8 + kh * 4 + ks2) * 512 + s;
          ((bf8*)Wch)[it] = *(const bf8*)(w2h + src);
          ((bf8*)Wcl)[it] = *(const bf8*)(w2l + src);
        }
        __syncthreads();
#pragma unroll
        for (int ntl = 0; ntl < 4; ++ntl) {
          f32x4v c = acc[c2 * 4 + ntl];
#pragma unroll
          for (int ks2 = 0; ks2 < 4; ++ks2) {
            bf8 bh = *(const bf8*)&Wch[(ntl * 4 + ks2) * 512 + l * 8];
            bf8 bl = *(const bf8*)&Wcl[(ntl * 4 + ks2) * 512 + l * 8];
            c = mfma16(a2l[ks2], bh, c);
            c = mfma16(a2h[ks2], bl, c);
            c = mfma16(a2h[ks2], bh, c);
          }
          acc[c2 * 4 + ntl] = c;
        }
      }
    }
    // ---- epilogue: in-place write + BN2 stats
    int base = tb * 64 + w * 16;
#pragma unroll
    for (int nt = 0; nt < 8; ++nt) {
      int cc = nt * 16 + l15;
#pragma unroll
      for (int r = 0; r < 4; ++r) {
        int gr = base + lg * 4 + r;
        if (gr < M) {
          float vv = acc[nt][r];
          A[(size_t)gr * 128 + cc] = vv;
          sAcc[nt] += vv;
          qAcc[nt] = fmaf(vv, vv, qAcc[nt]);
        }
      }
    }
  }
  __syncthreads();
#pragma unroll
  for (int nt = 0; nt < 8; ++nt) {
    float s = sAcc[nt], q = qAcc[nt];
    s += __shfl_xor(s, 16); s += __shfl_xor(s, 32);
    q += __shfl_xor(q, 16); q += __shfl_xor(q, 32);
    if (l < 16) { atomicAdd(&sRed[nt * 16 + l], s); atomicAdd(&qRed[nt * 16 + l], q); }
  }
  __syncthreads();
  if (tid < 128) { atomicAdd(&ssum[tid], sRed[tid]); atomicAdd(&ssq[tid], qRed[tid]); }
}

// ---------------- MFMA 128x128 GEMM: Out=Out+relu((A*aux)@W); Out2=Out (W in LDS) ----------------

__global__ __launch_bounds__(256) void gemm128_mfma_k(
    const float* __restrict__ A0, const float* __restrict__ AUX,
    const short* __restrict__ wh, const short* __restrict__ wl,
    float* __restrict__ Out, float* __restrict__ Out2, int M, int ntiles) {
  __shared__ __align__(16) short Wh[16384], Wl[16384];
  int tid = threadIdx.x;
  for (int i = tid; i < 2048; i += 256) {
    ((f32x4v*)Wh)[i] = ((const f32x4v*)wh)[i];
    ((f32x4v*)Wl)[i] = ((const f32x4v*)wl)[i];
  }
  __syncthreads();
  int w = tid >> 6, l = tid & 63, l15 = l & 15, lg = l >> 4;
  for (int tb = blockIdx.x; tb < ntiles; tb += gridDim.x) {
    int arow = tb * 64 + w * 16 + l15;
    bool av = arow < M;
    float sc = av ? AUX[arow] : 0.f;
    bf8 ah[4], al_[4];
    load_afrags(A0 + (size_t)arow * 128 + lg * 8, av, sc, ah, al_);
    int base = tb * 64 + w * 16;
#pragma unroll
    for (int nt = 0; nt < 8; ++nt) {
      f32x4v c = {0.f, 0.f, 0.f, 0.f};
#pragma unroll
      for (int ks = 0; ks < 4; ++ks) {
        bf8 bh = *(const bf8*)&Wh[(nt * 4 + ks) * 512 + l * 8];
        bf8 bl = *(const bf8*)&Wl[(nt * 4 + ks) * 512 + l * 8];
        c = mfma16(al_[ks], bh, c);
        c = mfma16(ah[ks], bl, c);
        c = mfma16(ah[ks], bh, c);
      }
#pragma unroll
      for (int r = 0; r < 4; ++r) {
        int gr = base + lg * 4 + r;
        if (gr < M) {
          size_t o = (size_t)gr * 128 + nt * 16 + l15;
          float t = Out[o] + fmaxf(c[r], 0.f);
          Out[o] = t;
          Out2[o] = t;
        }
      }
    }
  }
}

// ---------------- f32 GEMM for readout (small) ----------------
template<int PRO, int EPI>
__global__ __launch_bounds__(256) void gemm_k(
    const float* __restrict__ A0, const float* __restrict__ AUX,
    const float* __restrict__ W, float* __restrict__ Out, int M) {
  __shared__ __align__(16) float Ash[64][64];
  int tid = threadIdx.x;
  int tc = tid & 63, tr = tid >> 6;
  int row0 = blockIdx.x * 64;
  float acc[16][2];
#pragma unroll
  for (int i = 0; i < 16; ++i) { acc[i][0] = 0.f; acc[i][1] = 0.f; }
  for (int k0 = 0; k0 < 128; k0 += 64) {
#pragma unroll
    for (int it = 0; it < 4; ++it) {
      int fidx = tid + it * 256;
      int r = fidx >> 4, c4 = (fidx & 15) << 2;
      int gr = row0 + r;
      float4 v = make_float4(0.f, 0.f, 0.f, 0.f);
      if (gr < M) {
        v = *(const float4*)(A0 + (size_t)gr * 128 + k0 + c4);
        if (PRO == 2) { float s = AUX[gr]; v.x *= s; v.y *= s; v.z *= s; v.w *= s; }
      }
      *(float4*)&Ash[r][c4] = v;
    }
    __syncthreads();
    const float* Wp = W + (size_t)k0 * 128 + tc;
    for (int kk = 0; kk < 64; kk += 4) {
      float w[4][2];
#pragma unroll
      for (int kj = 0; kj < 4; ++kj)
#pragma unroll
        for (int j = 0; j < 2; ++j) w[kj][j] = Wp[(size_t)(kk + kj) * 128 + j * 64];
#pragma unroll
      for (int i = 0; i < 16; ++i) {
        float4 a = *(const float4*)&Ash[tr * 16 + i][kk];
#pragma unroll
        for (int j = 0; j < 2; ++j) {
          acc[i][j] = fmaf(a.x, w[0][j], acc[i][j]);
          acc[i][j] = fmaf(a.y, w[1][j], acc[i][j]);
          acc[i][j] = fmaf(a.z, w[2][j], acc[i][j]);
          acc[i][j] = fmaf(a.w, w[3][j], acc[i][j]);
        }
      }
    }
    __syncthreads();
  }
#pragma unroll
  for (int i = 0; i < 16; ++i) {
    int gr = row0 + tr * 16 + i;
    if (gr < M) {
#pragma unroll
      for (int j = 0; j < 2; ++j) {
        size_t o = (size_t)gr * 128 + tc + j * 64;
        float v = acc[i][j];
        if (EPI == 0) Out[o] = v;
        else Out[o] = fmaxf(Out[o] + v, 0.f);
      }
    }
  }
}

// ---------------- host ----------------

static inline int cdivll(long long a, long long b) { return (int)((a + b - 1) / b); }

extern "C" void kernel_launch(void* const* d_in, const int* in_sizes, int n_in,
                              void* d_out, int out_size, void* d_ws, size_t ws_size,
                              hipStream_t stream) {
  const int* node_feat  = (const int*)d_in[0];
  const int* edge_index = (const int*)d_in[1];
  const int* edge_feat  = (const int*)d_in[2];
  const int* batch      = (const int*)d_in[3];
  const int* map_row    = (const int*)d_in[4];
  const int* map_col    = (const int*)d_in[5];
  const int* rg_ei      = (const int*)d_in[6];
  const int* rg_feat    = (const int*)d_in[7];
  const int* tree_batch = (const int*)d_in[8];
  const float* atom_emb   = (const float*)d_in[10];
  const float* bond_emb   = (const float*)d_in[11];
  const float* rg_emb     = (const float*)d_in[12];
  const float* atom_W1    = (const float*)d_in[13];
  const float* atom_W2    = (const float*)d_in[14];
  const float* rg_W1      = (const float*)d_in[15];
  const float* rg_W2      = (const float*)d_in[16];
  const float* raw2rg_W   = (const float*)d_in[17];
  const float* rg2raw_W   = (const float*)d_in[18];
  const float* atom_lin_W = (const float*)d_in[19];
  const float* rg_lin_W   = (const float*)d_in[20];
  const float* lin_W      = (const float*)d_in[21];

  const int N   = in_sizes[0] / 9;
  const int E   = in_sizes[1] / 2;
  const int M   = in_sizes[4];
  const int NRG = in_sizes[7];
  const int ERG = in_sizes[6] / 2;
  const int G   = out_size / H;
  if (N <= 0 || G <= 0) return;

  const size_t NH = (size_t)N * H, RH = (size_t)NRG * H, GH = (size_t)G * H;
  const size_t need = 2 * NH + RH + (size_t)NRG + (size_t)N + 2 * (size_t)G + 1024 + 500000;
  if (ws_size < need * sizeof(float)) return;

  float* ws = (float*)d_ws;
  size_t off = 0;
  auto alloc = [&](size_t n) { float* p = ws + off; off += n; return p; };
  float* x    = alloc(NH);
  float* abuf = alloc(NH);
  float* rg   = alloc(RH);
  float* cnt_col   = alloc((size_t)NRG);
  float* cnt_row   = alloc((size_t)N);
  float* cnt_batch = alloc((size_t)G);
  float* cnt_tree  = alloc((size_t)G);
  float* ssum = alloc(256);
  float* ssq  = alloc(256);
  float* mu   = alloc(256);
  float* rsig = alloc(256);
  off = (off + 3) & ~(size_t)3;
  short* sp = (short*)(ws + off);
  size_t soff = 0;
  auto salloc = [&](size_t n) { short* p = sp + soff; soff += n; return p; };
  short* paW1h = salloc(3 * 32768); short* paW1l = salloc(3 * 32768);
  short* paW2h = salloc(3 * 32768); short* paW2l = salloc(3 * 32768);
  short* prW1h = salloc(3 * 32768); short* prW1l = salloc(3 * 32768);
  short* prW2h = salloc(3 * 32768); short* prW2l = salloc(3 * 32768);
  short* p2gh  = salloc(3 * 16384); short* p2gl  = salloc(3 * 16384);
  short* pg2h  = salloc(3 * 16384); short* pg2l  = salloc(3 * 16384);

  const int ta = (N + 63) >> 6, trg = (NRG + 63) >> 6;
  const int ga = ta < 512 ? ta : 512, grg = trg < 512 ? trg : 512;

  // ---- pack weights ----
  pack_w_k<<<dim3(128, 3), 256, 0, stream>>>(atom_W1, paW1h, paW1l, 128, 256);
  pack_w_k<<<dim3(128, 3), 256, 0, stream>>>(atom_W2, paW2h, paW2l, 256, 128);
  pack_w_k<<<dim3(128, 3), 256, 0, stream>>>(rg_W1, prW1h, prW1l, 128, 256);
  pack_w_k<<<dim3(128, 3), 256, 0, stream>>>(rg_W2, prW2h, prW2l, 256, 128);
  pack_w_k<<<dim3(64, 3), 256, 0, stream>>>(raw2rg_W, p2gh, p2gl, 128, 128);
  pack_w_k<<<dim3(64, 3), 256, 0, stream>>>(rg2raw_W, pg2h, pg2l, 128, 128);

  // ---- counts ----
  hipMemsetAsync(cnt_col, 0, (size_t)(NRG + N + 2 * G) * 4, stream);
  count_k<<<cdivll(M, 256), 256, 0, stream>>>(map_col, cnt_col, M);
  count_k<<<cdivll(M, 256), 256, 0, stream>>>(map_row, cnt_row, M);
  count_k<<<cdivll(N, 256), 256, 0, stream>>>(batch, cnt_batch, N);
  count_k<<<cdivll(NRG, 256), 256, 0, stream>>>(tree_batch, cnt_tree, NRG);
  inv_k<<<cdivll(NRG + N + 2 * G, 256), 256, 0, stream>>>(cnt_col, NRG + N + 2 * G);

  // ---- encoders ----
  atom_encode_k<<<cdivll(NH, 256), 256, 0, stream>>>(node_feat, atom_emb, x, abuf, N);
  rg_init_k<<<cdivll(RH, 256), 256, 0, stream>>>(rg_feat, rg_emb, rg, NRG);

  for (int i = 0; i < 3; ++i) {
    // --- GINE: abuf = x + agg ---
    edge_msg_k<<<cdivll((long long)E * H, 256), 256, 0, stream>>>(
        edge_index, edge_feat, bond_emb + (size_t)i * 3 * 100 * H, x, abuf, E);
    // --- atom MLP (MFMA) ---
    hipMemsetAsync(ssum, 0, 512 * 4, stream);
    mlp_stats_mfma_k<<<ga, 256, 0, stream>>>(abuf, paW1h + i * 32768, paW1l + i * 32768, ssum, ssq, N, ta);
    bn_final_k<<<1, 256, 0, stream>>>(ssum, ssq, mu, rsig, 256, 1.0f / N);
    hipMemsetAsync(ssum, 0, 512 * 4, stream);
    mlp_fused_mfma_k<<<ga, 256, 0, stream>>>(abuf, paW1h + i * 32768, paW1l + i * 32768,
        paW2h + i * 32768, paW2l + i * 32768, mu, rsig, ssum, ssq, N, ta);
    bn_final_k<<<1, 256, 0, stream>>>(ssum, ssq, mu, rsig, 128, 1.0f / N);
    bn_apply_relu_k<<<cdivll((long long)N * 32, 256), 256, 0, stream>>>(abuf, mu, rsig, x, N);

    // --- raw -> rg ---
    hipMemsetAsync(abuf, 0, RH * 4, stream);
    scatter_add_k<<<cdivll((long long)M * H, 256), 256, 0, stream>>>(map_row, map_col, x, abuf, M);
    gemm128_mfma_k<<<grg, 256, 0, stream>>>(abuf, cnt_col, p2gh + i * 16384, p2gl + i * 16384,
        rg, abuf, NRG, trg);

    // --- rg GIN ---
    scatter_add_k<<<cdivll((long long)ERG * H, 256), 256, 0, stream>>>(rg_ei, rg_ei + ERG, rg, abuf, ERG);
    hipMemsetAsync(ssum, 0, 512 * 4, stream);
    mlp_stats_mfma_k<<<grg, 256, 0, stream>>>(abuf, prW1h + i * 32768, prW1l + i * 32768, ssum, ssq, NRG, trg);
    bn_final_k<<<1, 256, 0, stream>>>(ssum, ssq, mu, rsig, 256, 1.0f / NRG);
    hipMemsetAsync(ssum, 0, 512 * 4, stream);
    mlp_fused_mfma_k<<<grg, 256, 0, stream>>>(abuf, prW1h + i * 32768, prW1l + i * 32768,
        prW2h + i * 32768, prW2l + i * 32768, mu, rsig, ssum, ssq, NRG, trg);
    bn_final_k<<<1, 256, 0, stream>>>(ssum, ssq, mu, rsig, 128, 1.0f / NRG);
    bn_apply_relu_k<<<cdivll((long long)NRG * 32, 256), 256, 0, stream>>>(abuf, mu, rsig, rg, NRG);

    // --- rg -> raw ---
    hipMemsetAsync(abuf, 0, NH * 4, stream);
    scatter_add_k<<<cdivll((long long)M * H, 256), 256, 0, stream>>>(map_col, map_row, rg, abuf, M);
    gemm128_mfma_k<<<ga, 256, 0, stream>>>(abuf, cnt_row, pg2h + i * 16384, pg2l + i * 16384,
        x, abuf, N, ta);
  }

  // ---- readout ----
  float* xg  = abuf;
  float* rgg = abuf + GH;
  float* P   = abuf + 2 * GH;
  hipMemsetAsync(abuf, 0, 2 * GH * 4, stream);
  scatter_add_k<<<cdivll(NH, 256), 256, 0, stream>>>(nullptr, batch, x, xg, N);
  scatter_add_k<<<cdivll(RH, 256), 256, 0, stream>>>(nullptr, tree_batch, rg, rgg, NRG);
  gemm_k<2, 0><<<cdivll(G, 64), 256, 0, stream>>>(xg, cnt_batch, atom_lin_W, P, G);
  gemm_k<2, 2><<<cdivll(G, 64), 256, 0, stream>>>(rgg, cnt_tree, rg_lin_W, P, G);
  gemm_k<0, 0><<<cdivll(G, 64), 256, 0, stream>>>(P, nullptr, lin_W, (float*)d_out, G);
}

// Round 6
// 4154.370 us; speedup vs baseline: 2.3156x; 1.0543x over previous
//
#include <hip/hip_runtime.h>
#include <hip/hip_bf16.h>
#include <cstdint>
#include <cstddef>

#define H 128

using f32x4v = __attribute__((ext_vector_type(4))) float;
using bf8 = __attribute__((ext_vector_type(8))) short;

__device__ __forceinline__ short f2bf(float f) {
  unsigned u = __float_as_uint(f);
  u = (u + 0x7fffu + ((u >> 16) & 1u)) >> 16;
  return (short)u;
}
__device__ __forceinline__ float bf2f(short h) {
  return __uint_as_float(((unsigned)(unsigned short)h) << 16);
}
__device__ __forceinline__ void splitf(float f, short& h, short& l) {
  h = f2bf(f);
  l = f2bf(f - bf2f(h));
}
__device__ __forceinline__ f32x4v mfma16(bf8 a, bf8 b, f32x4v c) {
  return __builtin_amdgcn_mfma_f32_16x16x32_bf16(a, b, c, 0, 0, 0);
}

__device__ __forceinline__ void load_afrags(const float* __restrict__ Ap, bool av,
    float sc, bf8* ah, bf8* al_) {
#pragma unroll
  for (int ks = 0; ks < 4; ++ks) {
    float v[8];
    if (av) {
      f32x4v p0 = *(const f32x4v*)(Ap + ks * 32);
      f32x4v p1 = *(const f32x4v*)(Ap + ks * 32 + 4);
      v[0]=p0.x*sc; v[1]=p0.y*sc; v[2]=p0.z*sc; v[3]=p0.w*sc;
      v[4]=p1.x*sc; v[5]=p1.y*sc; v[6]=p1.z*sc; v[7]=p1.w*sc;
    } else {
#pragma unroll
      for (int j = 0; j < 8; ++j) v[j] = 0.f;
    }
#pragma unroll
    for (int j = 0; j < 8; ++j) { short hh, ll; splitf(v[j], hh, ll); ah[ks][j]=hh; al_[ks][j]=ll; }
  }
}

// ---------------- weight packing ----------------

__global__ __launch_bounds__(256) void pack_w_k(const float* __restrict__ W,
    short* __restrict__ hi, short* __restrict__ lo, int K, int N) {
  int total = K * N;
  int t = blockIdx.x * 256 + threadIdx.x;
  int layer = blockIdx.y;
  if (t >= total) return;
  int k = t / N, n = t - k * N;
  float f = W[(size_t)layer * total + t];
  short h, l; splitf(f, h, l);
  int nt = n >> 4, ks = k >> 5, kk = k & 31;
  int lane = (n & 15) | (((kk >> 3) & 3) << 4);
  size_t idx = (size_t)layer * total + ((size_t)(nt * (K >> 5) + ks) << 9) + lane * 8 + (kk & 7);
  hi[idx] = h; lo[idx] = l;
}

// ---------------- embedding / init ----------------

__global__ __launch_bounds__(256) void atom_encode_k(const int* __restrict__ nf,
    const float* __restrict__ emb, float* __restrict__ x, int N) {
  long long t = (long long)blockIdx.x * 256 + threadIdx.x;
  if (t >= (long long)N * H) return;
  int n = (int)(t >> 7), h = (int)(t & 127);
  const int* row = nf + (size_t)n * 9;
  float s = 0.f;
#pragma unroll
  for (int f = 0; f < 9; ++f) s += emb[((size_t)f * 100 + row[f]) * H + h];
  x[t] = s;
}

__global__ __launch_bounds__(256) void rg_init_k(const int* __restrict__ feat,
    const float* __restrict__ emb, float* __restrict__ rg, int NRG) {
  long long t = (long long)blockIdx.x * 256 + threadIdx.x;
  if (t >= (long long)NRG * H) return;
  int n = (int)(t >> 7), h = (int)(t & 127);
  rg[t] = emb[(size_t)feat[n] * H + h];
}

// ---------------- CSR build ----------------

__global__ __launch_bounds__(256) void icount_k(const int* __restrict__ idx,
    int* __restrict__ cnt, int n) {
  int t = blockIdx.x * 256 + threadIdx.x;
  if (t < n) atomicAdd(&cnt[idx[t]], 1);
}

__global__ __launch_bounds__(256) void inv_from_int_k(const int* __restrict__ c,
    float* __restrict__ inv, int n) {
  int t = blockIdx.x * 256 + threadIdx.x;
  if (t < n) inv[t] = 1.0f / (float)max(c[t], 1);
}

__global__ __launch_bounds__(256) void seg_blocksum_k(const int* __restrict__ cnt,
    int* __restrict__ bsum, int n) {
  __shared__ int red[256];
  int base = blockIdx.x * 1024;
  int s = 0;
  for (int i = threadIdx.x; i < 1024; i += 256) {
    int idx = base + i;
    s += (idx < n) ? cnt[idx] : 0;
  }
  red[threadIdx.x] = s; __syncthreads();
  for (int st = 128; st > 0; st >>= 1) {
    if (threadIdx.x < st) red[threadIdx.x] += red[threadIdx.x + st];
    __syncthreads();
  }
  if (threadIdx.x == 0) bsum[blockIdx.x] = red[0];
}

// writes off[] and cursor cur[] (= off); cnt and cur may alias (same-thread read-then-write)
__global__ __launch_bounds__(256) void seg_scan_k(const int* __restrict__ cnt,
    const int* __restrict__ bsum, int* __restrict__ off, int* __restrict__ cur,
    int n, int nblk) {
  __shared__ int pref;
  __shared__ int tsum[257];
  int b = blockIdx.x;
  if (threadIdx.x == 0) {
    int p = 0;
    for (int j = 0; j < b; ++j) p += bsum[j];
    pref = p;
  }
  int base = b * 1024 + threadIdx.x * 4;
  int v[4]; int s = 0;
#pragma unroll
  for (int j = 0; j < 4; ++j) { int idx = base + j; v[j] = (idx < n) ? cnt[idx] : 0; s += v[j]; }
  tsum[threadIdx.x + 1] = s;
  if (threadIdx.x == 0) tsum[0] = 0;
  __syncthreads();
  if (threadIdx.x == 0) { for (int j = 1; j <= 256; ++j) tsum[j] += tsum[j - 1]; }
  __syncthreads();
  int run = pref + tsum[threadIdx.x];
#pragma unroll
  for (int j = 0; j < 4; ++j) {
    int idx = base + j;
    if (idx < n) { off[idx] = run; cur[idx] = run; }
    run += v[j];
  }
  if (b == 0 && threadIdx.x == 0) {
    int tot = 0;
    for (int j = 0; j < nblk; ++j) tot += bsum[j];
    off[n] = tot;
  }
}

__global__ __launch_bounds__(256) void seg_fill_k(const int* __restrict__ idx,
    int* __restrict__ cur, int* __restrict__ ids, int n) {
  int t = blockIdx.x * 256 + threadIdx.x;
  if (t < n) { int p = atomicAdd(&cur[idx[t]], 1); ids[p] = t; }
}

// ---------------- gather aggregations (no atomics) ----------------

// out[n] = x[n] + sum_{e in CSR[n]} relu(x[src_e] + bond_e)
__global__ __launch_bounds__(256) void gine_agg_k(const int* __restrict__ off,
    const int* __restrict__ ids, const int* __restrict__ ei, const int* __restrict__ ef,
    const float* __restrict__ bemb, const float* __restrict__ x,
    float* __restrict__ out, int N) {
  int n = blockIdx.x * 2 + (threadIdx.x >> 7);
  if (n >= N) return;
  int c = threadIdx.x & 127;
  float acc = x[(size_t)n * H + c];
  int p0 = off[n], p1 = off[n + 1];
  for (int p = p0; p < p1; ++p) {
    int e = ids[p];
    int src = ei[e];
    const int* f = ef + (size_t)e * 3;
    float v = bemb[(size_t)f[0] * H + c]
            + bemb[((size_t)100 + f[1]) * H + c]
            + bemb[((size_t)200 + f[2]) * H + c];
    acc += fmaxf(x[(size_t)src * H + c] + v, 0.f);
  }
  out[(size_t)n * H + c] = acc;
}

// out[n] = (base?base[n]:0) + sum_{m in CSR[n]} src[ sidx ? sidx[m] : m ]
__global__ __launch_bounds__(256) void gather_agg_k(const int* __restrict__ off,
    const int* __restrict__ ids, const int* __restrict__ sidx,
    const float* __restrict__ src, const float* __restrict__ base,
    float* __restrict__ out, int N) {
  int n = blockIdx.x * 2 + (threadIdx.x >> 7);
  if (n >= N) return;
  int c = threadIdx.x & 127;
  float acc = base ? base[(size_t)n * H + c] : 0.f;
  int p0 = off[n], p1 = off[n + 1];
  for (int p = p0; p < p1; ++p) {
    int m = ids[p];
    int sr = sidx ? sidx[m] : m;
    acc += src[(size_t)sr * H + c];
  }
  out[(size_t)n * H + c] = acc;
}

// mean pooling over sorted segment index (binary search boundaries)
__device__ __forceinline__ int lowb(const int* __restrict__ a, int n, int v) {
  int lo = 0, hi = n;
  while (lo < hi) { int mid = (lo + hi) >> 1; if (a[mid] < v) lo = mid + 1; else hi = mid; }
  return lo;
}

__global__ __launch_bounds__(256) void pool_mean_k(const int* __restrict__ bidx,
    const float* __restrict__ src, float* __restrict__ out, int n, int G) {
  int g = blockIdx.x * 2 + (threadIdx.x >> 7);
  if (g >= G) return;
  int c = threadIdx.x & 127;
  int lo = lowb(bidx, n, g), hi = lowb(bidx, n, g + 1);
  float acc = 0.f;
  for (int r = lo; r < hi; ++r) acc += src[(size_t)r * H + c];
  out[(size_t)g * H + c] = acc * (1.0f / (float)max(hi - lo, 1));
}

// ---------------- batchnorm helpers ----------------

__global__ void bn_final_k(const float* __restrict__ ssum, const float* __restrict__ ssq,
    float* __restrict__ mu, float* __restrict__ rsig, int C, float invM) {
  int c = threadIdx.x + blockIdx.x * blockDim.x;
  if (c < C) {
    float m = ssum[c] * invM;
    float v = ssq[c] * invM - m * m;
    mu[c] = m;
    rsig[c] = rsqrtf(v + 1e-5f);
  }
}

__global__ __launch_bounds__(256) void bn_apply_relu_k(const float* __restrict__ X,
    const float* __restrict__ mu, const float* __restrict__ rsig,
    float* __restrict__ Out, int M) {
  long long t = (long long)blockIdx.x * 256 + threadIdx.x;
  if (t >= (long long)M * 32) return;
  int c4 = ((int)(t & 31)) * 4;
  float4 v = ((const float4*)X)[t];
  float4 m4 = *(const float4*)&mu[c4];
  float4 r4 = *(const float4*)&rsig[c4];
  v.x = fmaxf((v.x - m4.x) * r4.x, 0.f);
  v.y = fmaxf((v.y - m4.y) * r4.y, 0.f);
  v.z = fmaxf((v.z - m4.z) * r4.z, 0.f);
  v.w = fmaxf((v.w - m4.w) * r4.w, 0.f);
  ((float4*)Out)[t] = v;
}

// ---------------- MFMA MLP stats (W1 LDS-chunked, barrier-fenced) ----------------

__global__ __launch_bounds__(256) void mlp_stats_mfma_k(
    const float* __restrict__ A, const short* __restrict__ w1h, const short* __restrict__ w1l,
    float* __restrict__ ssum, float* __restrict__ ssq, int M, int ntiles) {
  __shared__ __align__(16) short Wch[8192], Wcl[8192];
  __shared__ float sRed[256], qRed[256];
  int tid = threadIdx.x;
  sRed[tid] = 0.f; qRed[tid] = 0.f;
  int w = tid >> 6, l = tid & 63, l15 = l & 15, lg = l >> 4;
  float sAcc[16], qAcc[16];
#pragma unroll
  for (int nt = 0; nt < 16; ++nt) { sAcc[nt] = 0.f; qAcc[nt] = 0.f; }
  for (int tb = blockIdx.x; tb < ntiles; tb += gridDim.x) {
    int arow = tb * 64 + w * 16 + l15;
    bool av = arow < M;
    bf8 ah[4], al_[4];
    load_afrags(A + (size_t)arow * 128 + lg * 8, av, 1.f, ah, al_);
    for (int ch = 0; ch < 4; ++ch) {
      __syncthreads();
      const bf8* srcH = (const bf8*)(w1h + ch * 8192);
      const bf8* srcL = (const bf8*)(w1l + ch * 8192);
      for (int it = tid; it < 1024; it += 256) {
        ((bf8*)Wch)[it] = srcH[it];
        ((bf8*)Wcl)[it] = srcL[it];
      }
      __syncthreads();
#pragma unroll
      for (int ntl = 0; ntl < 4; ++ntl) {
        f32x4v c = {0.f, 0.f, 0.f, 0.f};
#pragma unroll
        for (int ks = 0; ks < 4; ++ks) {
          bf8 bh = *(const bf8*)&Wch[(ntl * 4 + ks) * 512 + l * 8];
          bf8 bl = *(const bf8*)&Wcl[(ntl * 4 + ks) * 512 + l * 8];
          c = mfma16(al_[ks], bh, c);
          c = mfma16(ah[ks], bl, c);
          c = mfma16(ah[ks], bh, c);
        }
        int nt = ch * 4 + ntl;
        sAcc[nt] += c[0] + c[1] + c[2] + c[3];
        qAcc[nt] += c[0]*c[0] + c[1]*c[1] + c[2]*c[2] + c[3]*c[3];
      }
    }
  }
  __syncthreads();
#pragma unroll
  for (int nt = 0; nt < 16; ++nt) {
    float s = sAcc[nt], q = qAcc[nt];
    s += __shfl_xor(s, 16); s += __shfl_xor(s, 32);
    q += __shfl_xor(q, 16); q += __shfl_xor(q, 32);
    if (l < 16) { atomicAdd(&sRed[nt * 16 + l], s); atomicAdd(&qRed[nt * 16 + l], q); }
  }
  __syncthreads();
  atomicAdd(&ssum[tid], sRed[tid]);
  atomicAdd(&ssq[tid], qRed[tid]);
}

// ---------------- MFMA fused MLP (h1 in LDS f32, W chunks barrier-fenced) ----------------

__global__ __launch_bounds__(256) void mlp_fused_mfma_k(
    float* __restrict__ A, const short* __restrict__ w1h, const short* __restrict__ w1l,
    const short* __restrict__ w2h, const short* __restrict__ w2l,
    const float* __restrict__ mu, const float* __restrict__ rsig,
    float* __restrict__ ssum, float* __restrict__ ssq, int M, int ntiles) {
  __shared__ __align__(16) short Wch[8192], Wcl[8192];
  __shared__ __align__(16) float h1f[64][132];
  __shared__ float sRed[128], qRed[128];
  int tid = threadIdx.x;
  if (tid < 128) { sRed[tid] = 0.f; qRed[tid] = 0.f; }
  int w = tid >> 6, l = tid & 63, l15 = l & 15, lg = l >> 4;
  float sAcc[8], qAcc[8];
#pragma unroll
  for (int nt = 0; nt < 8; ++nt) { sAcc[nt] = 0.f; qAcc[nt] = 0.f; }
  for (int tb = blockIdx.x; tb < ntiles; tb += gridDim.x) {
    int arow = tb * 64 + w * 16 + l15;
    bool av = arow < M;
    f32x4v acc[8];
#pragma unroll
    for (int nt = 0; nt < 8; ++nt) acc[nt] = (f32x4v){0.f, 0.f, 0.f, 0.f};
    for (int kh = 0; kh < 2; ++kh) {
      {
        bf8 ah[4], al_[4];
        load_afrags(A + (size_t)arow * 128 + lg * 8, av, 1.f, ah, al_);
        for (int ch = 0; ch < 2; ++ch) {
          int cbase = kh * 8 + ch * 4;
          __syncthreads();
          const bf8* srcH = (const bf8*)(w1h + cbase * 2048);
          const bf8* srcL = (const bf8*)(w1l + cbase * 2048);
          for (int it = tid; it < 1024; it += 256) {
            ((bf8*)Wch)[it] = srcH[it];
            ((bf8*)Wcl)[it] = srcL[it];
          }
          __syncthreads();
#pragma unroll
          for (int ntl = 0; ntl < 4; ++ntl) {
            f32x4v c = {0.f, 0.f, 0.f, 0.f};
#pragma unroll
            for (int ks = 0; ks < 4; ++ks) {
              bf8 bh = *(const bf8*)&Wch[(ntl * 4 + ks) * 512 + l * 8];
              bf8 bl = *(const bf8*)&Wcl[(ntl * 4 + ks) * 512 + l * 8];
              c = mfma16(al_[ks], bh, c);
              c = mfma16(ah[ks], bl, c);
              c = mfma16(ah[ks], bh, c);
            }
            int cn = cbase + ntl;
            int cc = cn * 16 + l15;
            float mm = mu[cc], rs = rsig[cc];
#pragma unroll
            for (int r = 0; r < 4; ++r) {
              float t = fmaxf((c[r] - mm) * rs, 0.f);
              h1f[w * 16 + lg * 4 + r][(cn & 7) * 16 + l15] = t;
            }
          }
        }
      }
      __syncthreads();
      bf8 a2h[4], a2l[4];
#pragma unroll
      for (int ks2 = 0; ks2 < 4; ++ks2) {
        const float* hp = &h1f[w * 16 + l15][ks2 * 32 + lg * 8];
#pragma unroll
        for (int j = 0; j < 8; ++j) {
          short hh, ll; splitf(hp[j], hh, ll);
          a2h[ks2][j] = hh; a2l[ks2][j] = ll;
        }
      }
      for (int c2 = 0; c2 < 2; ++c2) {
        __syncthreads();
        for (int it = tid; it < 1024; it += 256) {
          int e = it * 8;
          int ntl = e >> 11, rem = e & 2047;
          int ks2 = rem >> 9, s = rem & 511;
          int src = ((c2 * 4 + ntl) * 8 + kh * 4 + ks2) * 512 + s;
          ((bf8*)Wch)[it] = *(const bf8*)(w2h + src);
          ((bf8*)Wcl)[it] = *(const bf8*)(w2l + src);
        }
        __syncthreads();
#pragma unroll
        for (int ntl = 0; ntl < 4; ++ntl) {
          f32x4v c = acc[c2 * 4 + ntl];
#pragma unroll
          for (int ks2 = 0; ks2 < 4; ++ks2) {
            bf8 bh = *(const bf8*)&Wch[(ntl * 4 + ks2) * 512 + l * 8];
            bf8 bl = *(const bf8*)&Wcl[(ntl * 4 + ks2) * 512 + l * 8];
            c = mfma16(a2l[ks2], bh, c);
            c = mfma16(a2h[ks2], bl, c);
            c = mfma16(a2h[ks2], bh, c);
          }
          acc[c2 * 4 + ntl] = c;
        }
      }
    }
    int base = tb * 64 + w * 16;
#pragma unroll
    for (int nt = 0; nt < 8; ++nt) {
      int cc = nt * 16 + l15;
#pragma unroll
      for (int r = 0; r < 4; ++r) {
        int gr = base + lg * 4 + r;
        if (gr < M) {
          float vv = acc[nt][r];
          A[(size_t)gr * 128 + cc] = vv;
          sAcc[nt] += vv;
          qAcc[nt] = fmaf(vv, vv, qAcc[nt]);
        }
      }
    }
  }
  __syncthreads();
#pragma unroll
  for (int nt = 0; nt < 8; ++nt) {
    float s = sAcc[nt], q = qAcc[nt];
    s += __shfl_xor(s, 16); s += __shfl_xor(s, 32);
    q += __shfl_xor(q, 16); q += __shfl_xor(q, 32);
    if (l < 16) { atomicAdd(&sRed[nt * 16 + l], s); atomicAdd(&qRed[nt * 16 + l], q); }
  }
  __syncthreads();
  if (tid < 128) { atomicAdd(&ssum[tid], sRed[tid]); atomicAdd(&ssq[tid], qRed[tid]); }
}

// ---------------- MFMA 128x128 GEMM: Out = Out + relu((A*aux) @ W) ----------------

__global__ __launch_bounds__(256) void gemm128_mfma_k(
    const float* __restrict__ A0, const float* __restrict__ AUX,
    const short* __restrict__ wh, const short* __restrict__ wl,
    float* __restrict__ Out, int M, int ntiles) {
  __shared__ __align__(16) short Wh[16384], Wl[16384];
  int tid = threadIdx.x;
  for (int i = tid; i < 2048; i += 256) {
    ((f32x4v*)Wh)[i] = ((const f32x4v*)wh)[i];
    ((f32x4v*)Wl)[i] = ((const f32x4v*)wl)[i];
  }
  __syncthreads();
  int w = tid >> 6, l = tid & 63, l15 = l & 15, lg = l >> 4;
  for (int tb = blockIdx.x; tb < ntiles; tb += gridDim.x) {
    int arow = tb * 64 + w * 16 + l15;
    bool av = arow < M;
    float sc = av ? AUX[arow] : 0.f;
    bf8 ah[4], al_[4];
    load_afrags(A0 + (size_t)arow * 128 + lg * 8, av, sc, ah, al_);
    int base = tb * 64 + w * 16;
#pragma unroll
    for (int nt = 0; nt < 8; ++nt) {
      f32x4v c = {0.f, 0.f, 0.f, 0.f};
#pragma unroll
      for (int ks = 0; ks < 4; ++ks) {
        bf8 bh = *(const bf8*)&Wh[(nt * 4 + ks) * 512 + l * 8];
        bf8 bl = *(const bf8*)&Wl[(nt * 4 + ks) * 512 + l * 8];
        c = mfma16(al_[ks], bh, c);
        c = mfma16(ah[ks], bl, c);
        c = mfma16(ah[ks], bh, c);
      }
#pragma unroll
      for (int r = 0; r < 4; ++r) {
        int gr = base + lg * 4 + r;
        if (gr < M) {
          size_t o = (size_t)gr * 128 + nt * 16 + l15;
          Out[o] = Out[o] + fmaxf(c[r], 0.f);
        }
      }
    }
  }
}

// ---------------- f32 GEMM for readout ----------------
// EPI: 0 Out=acc, 2 Out=relu(Out+acc)
template<int EPI>
__global__ __launch_bounds__(256) void gemm_k(
    const float* __restrict__ A0, const float* __restrict__ W,
    float* __restrict__ Out, int M) {
  __shared__ __align__(16) float Ash[64][64];
  int tid = threadIdx.x;
  int tc = tid & 63, tr = tid >> 6;
  int row0 = blockIdx.x * 64;
  float acc[16][2];
#pragma unroll
  for (int i = 0; i < 16; ++i) { acc[i][0] = 0.f; acc[i][1] = 0.f; }
  for (int k0 = 0; k0 < 128; k0 += 64) {
#pragma unroll
    for (int it = 0; it < 4; ++it) {
      int fidx = tid + it * 256;
      int r = fidx >> 4, c4 = (fidx & 15) << 2;
      int gr = row0 + r;
      float4 v = make_float4(0.f, 0.f, 0.f, 0.f);
      if (gr < M) v = *(const float4*)(A0 + (size_t)gr * 128 + k0 + c4);
      *(float4*)&Ash[r][c4] = v;
    }
    __syncthreads();
    const float* Wp = W + (size_t)k0 * 128 + tc;
    for (int kk = 0; kk < 64; kk += 4) {
      float w[4][2];
#pragma unroll
      for (int kj = 0; kj < 4; ++kj)
#pragma unroll
        for (int j = 0; j < 2; ++j) w[kj][j] = Wp[(size_t)(kk + kj) * 128 + j * 64];
#pragma unroll
      for (int i = 0; i < 16; ++i) {
        float4 a = *(const float4*)&Ash[tr * 16 + i][kk];
#pragma unroll
        for (int j = 0; j < 2; ++j) {
          acc[i][j] = fmaf(a.x, w[0][j], acc[i][j]);
          acc[i][j] = fmaf(a.y, w[1][j], acc[i][j]);
          acc[i][j] = fmaf(a.z, w[2][j], acc[i][j]);
          acc[i][j] = fmaf(a.w, w[3][j], acc[i][j]);
        }
      }
    }
    __syncthreads();
  }
#pragma unroll
  for (int i = 0; i < 16; ++i) {
    int gr = row0 + tr * 16 + i;
    if (gr < M) {
#pragma unroll
      for (int j = 0; j < 2; ++j) {
        size_t o = (size_t)gr * 128 + tc + j * 64;
        float v = acc[i][j];
        if (EPI == 0) Out[o] = v;
        else Out[o] = fmaxf(Out[o] + v, 0.f);
      }
    }
  }
}

// ---------------- host ----------------

static inline int cdivll(long long a, long long b) { return (int)((a + b - 1) / b); }

extern "C" void kernel_launch(void* const* d_in, const int* in_sizes, int n_in,
                              void* d_out, int out_size, void* d_ws, size_t ws_size,
                              hipStream_t stream) {
  const int* node_feat  = (const int*)d_in[0];
  const int* edge_index = (const int*)d_in[1];
  const int* edge_feat  = (const int*)d_in[2];
  const int* batch      = (const int*)d_in[3];
  const int* map_row    = (const int*)d_in[4];
  const int* map_col    = (const int*)d_in[5];
  const int* rg_ei      = (const int*)d_in[6];
  const int* rg_feat    = (const int*)d_in[7];
  const int* tree_batch = (const int*)d_in[8];
  const float* atom_emb   = (const float*)d_in[10];
  const float* bond_emb   = (const float*)d_in[11];
  const float* rg_emb     = (const float*)d_in[12];
  const float* atom_W1    = (const float*)d_in[13];
  const float* atom_W2    = (const float*)d_in[14];
  const float* rg_W1      = (const float*)d_in[15];
  const float* rg_W2      = (const float*)d_in[16];
  const float* raw2rg_W   = (const float*)d_in[17];
  const float* rg2raw_W   = (const float*)d_in[18];
  const float* atom_lin_W = (const float*)d_in[19];
  const float* rg_lin_W   = (const float*)d_in[20];
  const float* lin_W      = (const float*)d_in[21];

  const int N   = in_sizes[0] / 9;
  const int E   = in_sizes[1] / 2;
  const int M   = in_sizes[4];
  const int NRG = in_sizes[7];
  const int ERG = in_sizes[6] / 2;
  const int G   = out_size / H;
  if (N <= 0 || G <= 0) return;

  const size_t NH = (size_t)N * H, RH = (size_t)NRG * H, GH = (size_t)G * H;
  const int cmax = max(N, NRG);

  // float region
  const size_t nfloat = 2 * NH + RH + (size_t)NRG + (size_t)N + 1024;
  // int region
  const size_t nint = (size_t)(N + 1) * 2 + (size_t)(NRG + 1) * 2
                    + (size_t)E + 2 * (size_t)M + (size_t)ERG + (size_t)cmax + 1024;
  // short region
  const size_t nshort = 3 * (4 * 32768 + 2 * 16384);
  const size_t need = nfloat * 4 + nint * 4 + nshort * 2 + 256;
  if (ws_size < need) return;

  float* ws = (float*)d_ws;
  size_t off = 0;
  auto alloc = [&](size_t n) { float* p = ws + off; off += n; return p; };
  float* x       = alloc(NH);
  float* abuf    = alloc(NH);
  float* rg      = alloc(RH);
  float* inv_col = alloc((size_t)NRG);
  float* inv_row = alloc((size_t)N);
  float* ssum = alloc(256);
  float* ssq  = alloc(256);
  float* mu   = alloc(256);
  float* rsig = alloc(256);

  int* ip = (int*)(ws + off);
  size_t ioff = 0;
  auto ialloc = [&](size_t n) { int* p = ip + ioff; ioff += n; return p; };
  int* off_dst = ialloc((size_t)N + 1);
  int* off_col = ialloc((size_t)NRG + 1);
  int* off_row = ialloc((size_t)N + 1);
  int* off_rg  = ialloc((size_t)NRG + 1);
  int* ids_dst = ialloc((size_t)E);
  int* ids_col = ialloc((size_t)M);
  int* ids_row = ialloc((size_t)M);
  int* ids_rg  = ialloc((size_t)ERG);
  int* tmp_cnt = ialloc((size_t)cmax);
  int* bsum    = ialloc(1024);

  short* sp = (short*)(ip + ioff);
  size_t soff = 0;
  auto salloc = [&](size_t n) { short* p = sp + soff; soff += n; return p; };
  short* paW1h = salloc(3 * 32768); short* paW1l = salloc(3 * 32768);
  short* paW2h = salloc(3 * 32768); short* paW2l = salloc(3 * 32768);
  short* prW1h = salloc(3 * 32768); short* prW1l = salloc(3 * 32768);
  short* prW2h = salloc(3 * 32768); short* prW2l = salloc(3 * 32768);
  short* p2gh  = salloc(3 * 16384); short* p2gl  = salloc(3 * 16384);
  short* pg2h  = salloc(3 * 16384); short* pg2l  = salloc(3 * 16384);

  const int ta = (N + 63) >> 6, trg = (NRG + 63) >> 6;
  const int ga = ta < 512 ? ta : 512, grg = trg < 512 ? trg : 512;

  // ---- pack weights ----
  pack_w_k<<<dim3(128, 3), 256, 0, stream>>>(atom_W1, paW1h, paW1l, 128, 256);
  pack_w_k<<<dim3(128, 3), 256, 0, stream>>>(atom_W2, paW2h, paW2l, 256, 128);
  pack_w_k<<<dim3(128, 3), 256, 0, stream>>>(rg_W1, prW1h, prW1l, 128, 256);
  pack_w_k<<<dim3(128, 3), 256, 0, stream>>>(rg_W2, prW2h, prW2l, 256, 128);
  pack_w_k<<<dim3(64, 3), 256, 0, stream>>>(raw2rg_W, p2gh, p2gl, 128, 128);
  pack_w_k<<<dim3(64, 3), 256, 0, stream>>>(rg2raw_W, pg2h, pg2l, 128, 128);

  // ---- CSR builds (tmp_cnt doubles as cursor; counts→inv where needed) ----
  auto build_csr = [&](const int* idx, int nelem, int nrows, int* offs, int* ids,
                       float* inv) {
    hipMemsetAsync(tmp_cnt, 0, (size_t)nrows * 4, stream);
    icount_k<<<cdivll(nelem, 256), 256, 0, stream>>>(idx, tmp_cnt, nelem);
    if (inv) inv_from_int_k<<<cdivll(nrows, 256), 256, 0, stream>>>(tmp_cnt, inv, nrows);
    int nblk = cdivll(nrows, 1024);
    seg_blocksum_k<<<nblk, 256, 0, stream>>>(tmp_cnt, bsum, nrows);
    seg_scan_k<<<nblk, 256, 0, stream>>>(tmp_cnt, bsum, offs, tmp_cnt, nrows, nblk);
    seg_fill_k<<<cdivll(nelem, 256), 256, 0, stream>>>(idx, tmp_cnt, ids, nelem);
  };
  build_csr(edge_index + E, E, N, off_dst, ids_dst, nullptr);   // edges by dst
  build_csr(map_col, M, NRG, off_col, ids_col, inv_col);        // mapping by col
  build_csr(map_row, M, N, off_row, ids_row, inv_row);          // mapping by row
  build_csr(rg_ei + ERG, ERG, NRG, off_rg, ids_rg, nullptr);    // rg edges by rdst

  // ---- encoders ----
  atom_encode_k<<<cdivll(NH, 256), 256, 0, stream>>>(node_feat, atom_emb, x, N);
  rg_init_k<<<cdivll(RH, 256), 256, 0, stream>>>(rg_feat, rg_emb, rg, NRG);

  for (int i = 0; i < 3; ++i) {
    // --- GINE: abuf = x + sum relu(x[src]+e) (gathered) ---
    gine_agg_k<<<cdivll(N, 2), 256, 0, stream>>>(off_dst, ids_dst, edge_index, edge_feat,
        bond_emb + (size_t)i * 3 * 100 * H, x, abuf, N);
    // --- atom MLP (MFMA) ---
    hipMemsetAsync(ssum, 0, 512 * 4, stream);
    mlp_stats_mfma_k<<<ga, 256, 0, stream>>>(abuf, paW1h + i * 32768, paW1l + i * 32768, ssum, ssq, N, ta);
    bn_final_k<<<1, 256, 0, stream>>>(ssum, ssq, mu, rsig, 256, 1.0f / N);
    hipMemsetAsync(ssum, 0, 512 * 4, stream);
    mlp_fused_mfma_k<<<ga, 256, 0, stream>>>(abuf, paW1h + i * 32768, paW1l + i * 32768,
        paW2h + i * 32768, paW2l + i * 32768, mu, rsig, ssum, ssq, N, ta);
    bn_final_k<<<1, 256, 0, stream>>>(ssum, ssq, mu, rsig, 128, 1.0f / N);
    bn_apply_relu_k<<<cdivll((long long)N * 32, 256), 256, 0, stream>>>(abuf, mu, rsig, x, N);

    // --- raw -> rg: abuf[0:RH] = gathered sum; rg += relu(mean @ W) ---
    gather_agg_k<<<cdivll(NRG, 2), 256, 0, stream>>>(off_col, ids_col, map_row, x, nullptr, abuf, NRG);
    gemm128_mfma_k<<<grg, 256, 0, stream>>>(abuf, inv_col, p2gh + i * 16384, p2gl + i * 16384,
        rg, NRG, trg);

    // --- rg GIN: abuf = rg + sum rg[rsrc] (gathered) ---
    gather_agg_k<<<cdivll(NRG, 2), 256, 0, stream>>>(off_rg, ids_rg, rg_ei, rg, rg, abuf, NRG);
    hipMemsetAsync(ssum, 0, 512 * 4, stream);
    mlp_stats_mfma_k<<<grg, 256, 0, stream>>>(abuf, prW1h + i * 32768, prW1l + i * 32768, ssum, ssq, NRG, trg);
    bn_final_k<<<1, 256, 0, stream>>>(ssum, ssq, mu, rsig, 256, 1.0f / NRG);
    hipMemsetAsync(ssum, 0, 512 * 4, stream);
    mlp_fused_mfma_k<<<grg, 256, 0, stream>>>(abuf, prW1h + i * 32768, prW1l + i * 32768,
        prW2h + i * 32768, prW2l + i * 32768, mu, rsig, ssum, ssq, NRG, trg);
    bn_final_k<<<1, 256, 0, stream>>>(ssum, ssq, mu, rsig, 128, 1.0f / NRG);
    bn_apply_relu_k<<<cdivll((long long)NRG * 32, 256), 256, 0, stream>>>(abuf, mu, rsig, rg, NRG);

    // --- rg -> raw: abuf[0:NH] = gathered sum; x += relu(mean @ W) ---
    gather_agg_k<<<cdivll(N, 2), 256, 0, stream>>>(off_row, ids_row, map_col, rg, nullptr, abuf, N);
    gemm128_mfma_k<<<ga, 256, 0, stream>>>(abuf, inv_row, pg2h + i * 16384, pg2l + i * 16384,
        x, N, ta);
  }

  // ---- readout: segment-mean pooling (batch sorted) + small GEMMs ----
  float* xg  = abuf;
  float* rgg = abuf + GH;
  float* P   = abuf + 2 * GH;
  pool_mean_k<<<cdivll(G, 2), 256, 0, stream>>>(batch, x, xg, N, G);
  pool_mean_k<<<cdivll(G, 2), 256, 0, stream>>>(tree_batch, rg, rgg, NRG, G);
  gemm_k<0><<<cdivll(G, 64), 256, 0, stream>>>(xg, atom_lin_W, P, G);
  gemm_k<2><<<cdivll(G, 64), 256, 0, stream>>>(rgg, rg_lin_W, P, G);
  gemm_k<0><<<cdivll(G, 64), 256, 0, stream>>>(P, lin_W, (float*)d_out, G);
}

// Round 7
// 3198.329 us; speedup vs baseline: 3.0078x; 1.2989x over previous
//
#include <hip/hip_runtime.h>
#include <hip/hip_bf16.h>
#include <cstdint>
#include <cstddef>

#define H 128

using f32x4v = __attribute__((ext_vector_type(4))) float;
using bf8 = __attribute__((ext_vector_type(8))) short;

__device__ __forceinline__ short f2bf(float f) {
  unsigned u = __float_as_uint(f);
  u = (u + 0x7fffu + ((u >> 16) & 1u)) >> 16;
  return (short)u;
}
__device__ __forceinline__ float bf2f(short h) {
  return __uint_as_float(((unsigned)(unsigned short)h) << 16);
}
__device__ __forceinline__ void splitf(float f, short& h, short& l) {
  h = f2bf(f);
  l = f2bf(f - bf2f(h));
}
__device__ __forceinline__ f32x4v mfma16(bf8 a, bf8 b, f32x4v c) {
  return __builtin_amdgcn_mfma_f32_16x16x32_bf16(a, b, c, 0, 0, 0);
}

__device__ __forceinline__ void load_afrags(const float* __restrict__ Ap, bool av,
    float sc, bf8* ah, bf8* al_) {
#pragma unroll
  for (int ks = 0; ks < 4; ++ks) {
    float v[8];
    if (av) {
      f32x4v p0 = *(const f32x4v*)(Ap + ks * 32);
      f32x4v p1 = *(const f32x4v*)(Ap + ks * 32 + 4);
      v[0]=p0.x*sc; v[1]=p0.y*sc; v[2]=p0.z*sc; v[3]=p0.w*sc;
      v[4]=p1.x*sc; v[5]=p1.y*sc; v[6]=p1.z*sc; v[7]=p1.w*sc;
    } else {
#pragma unroll
      for (int j = 0; j < 8; ++j) v[j] = 0.f;
    }
#pragma unroll
    for (int j = 0; j < 8; ++j) { short hh, ll; splitf(v[j], hh, ll); ah[ks][j]=hh; al_[ks][j]=ll; }
  }
}

// ---------------- weight packing ----------------

__global__ __launch_bounds__(256) void pack_w_k(const float* __restrict__ W,
    short* __restrict__ hi, short* __restrict__ lo, int K, int N) {
  int total = K * N;
  int t = blockIdx.x * 256 + threadIdx.x;
  int layer = blockIdx.y;
  if (t >= total) return;
  int k = t / N, n = t - k * N;
  float f = W[(size_t)layer * total + t];
  short h, l; splitf(f, h, l);
  int nt = n >> 4, ks = k >> 5, kk = k & 31;
  int lane = (n & 15) | (((kk >> 3) & 3) << 4);
  size_t idx = (size_t)layer * total + ((size_t)(nt * (K >> 5) + ks) << 9) + lane * 8 + (kk & 7);
  hi[idx] = h; lo[idx] = l;
}

// ---------------- embedding / init ----------------

__global__ __launch_bounds__(256) void atom_encode_k(const int* __restrict__ nf,
    const float* __restrict__ emb, float* __restrict__ x, int N) {
  long long t = (long long)blockIdx.x * 256 + threadIdx.x;
  if (t >= (long long)N * H) return;
  int n = (int)(t >> 7), h = (int)(t & 127);
  const int* row = nf + (size_t)n * 9;
  float s = 0.f;
#pragma unroll
  for (int f = 0; f < 9; ++f) s += emb[((size_t)f * 100 + row[f]) * H + h];
  x[t] = s;
}

__global__ __launch_bounds__(256) void rg_init_k(const int* __restrict__ feat,
    const float* __restrict__ emb, float* __restrict__ rg, int NRG) {
  long long t = (long long)blockIdx.x * 256 + threadIdx.x;
  if (t >= (long long)NRG * H) return;
  int n = (int)(t >> 7), h = (int)(t & 127);
  rg[t] = emb[(size_t)feat[n] * H + h];
}

// ---------------- CSR build ----------------

__global__ __launch_bounds__(256) void icount_k(const int* __restrict__ idx,
    int* __restrict__ cnt, int n) {
  int t = blockIdx.x * 256 + threadIdx.x;
  if (t < n) atomicAdd(&cnt[idx[t]], 1);
}

__global__ __launch_bounds__(256) void inv_from_int_k(const int* __restrict__ c,
    float* __restrict__ inv, int n) {
  int t = blockIdx.x * 256 + threadIdx.x;
  if (t < n) inv[t] = 1.0f / (float)max(c[t], 1);
}

__global__ __launch_bounds__(256) void seg_blocksum_k(const int* __restrict__ cnt,
    int* __restrict__ bsum, int n) {
  __shared__ int red[256];
  int base = blockIdx.x * 1024;
  int s = 0;
  for (int i = threadIdx.x; i < 1024; i += 256) {
    int idx = base + i;
    s += (idx < n) ? cnt[idx] : 0;
  }
  red[threadIdx.x] = s; __syncthreads();
  for (int st = 128; st > 0; st >>= 1) {
    if (threadIdx.x < st) red[threadIdx.x] += red[threadIdx.x + st];
    __syncthreads();
  }
  if (threadIdx.x == 0) bsum[blockIdx.x] = red[0];
}

__global__ __launch_bounds__(256) void seg_scan_k(const int* __restrict__ cnt,
    const int* __restrict__ bsum, int* __restrict__ off, int* __restrict__ cur,
    int n, int nblk) {
  __shared__ int pref;
  __shared__ int tsum[257];
  int b = blockIdx.x;
  if (threadIdx.x == 0) {
    int p = 0;
    for (int j = 0; j < b; ++j) p += bsum[j];
    pref = p;
  }
  int base = b * 1024 + threadIdx.x * 4;
  int v[4]; int s = 0;
#pragma unroll
  for (int j = 0; j < 4; ++j) { int idx = base + j; v[j] = (idx < n) ? cnt[idx] : 0; s += v[j]; }
  tsum[threadIdx.x + 1] = s;
  if (threadIdx.x == 0) tsum[0] = 0;
  __syncthreads();
  if (threadIdx.x == 0) { for (int j = 1; j <= 256; ++j) tsum[j] += tsum[j - 1]; }
  __syncthreads();
  int run = pref + tsum[threadIdx.x];
#pragma unroll
  for (int j = 0; j < 4; ++j) {
    int idx = base + j;
    if (idx < n) { off[idx] = run; cur[idx] = run; }
    run += v[j];
  }
  if (b == 0 && threadIdx.x == 0) {
    int tot = 0;
    for (int j = 0; j < nblk; ++j) tot += bsum[j];
    off[n] = tot;
  }
}

__global__ __launch_bounds__(256) void seg_fill_k(const int* __restrict__ idx,
    int* __restrict__ cur, int* __restrict__ ids, int n) {
  int t = blockIdx.x * 256 + threadIdx.x;
  if (t < n) { int p = atomicAdd(&cur[idx[t]], 1); ids[p] = t; }
}

// ---------------- gather aggregations (float4, 8 rows/block) ----------------

__global__ __launch_bounds__(256) void gine_agg_k(const int* __restrict__ off,
    const int* __restrict__ ids, const int* __restrict__ ei, const int* __restrict__ ef,
    const float* __restrict__ bemb, const float* __restrict__ x,
    float* __restrict__ out, int N) {
  int n = blockIdx.x * 8 + (threadIdx.x >> 5);
  if (n >= N) return;
  int c4 = (threadIdx.x & 31) * 4;
  float4 acc = *(const float4*)(x + (size_t)n * H + c4);
  int p0 = off[n], p1 = off[n + 1];
  for (int p = p0; p < p1; ++p) {
    int e = ids[p];
    int src = ei[e];
    const int* f = ef + (size_t)e * 3;
    float4 v0 = *(const float4*)(bemb + (size_t)f[0] * H + c4);
    float4 v1 = *(const float4*)(bemb + ((size_t)100 + f[1]) * H + c4);
    float4 v2 = *(const float4*)(bemb + ((size_t)200 + f[2]) * H + c4);
    float4 xs = *(const float4*)(x + (size_t)src * H + c4);
    acc.x += fmaxf(xs.x + v0.x + v1.x + v2.x, 0.f);
    acc.y += fmaxf(xs.y + v0.y + v1.y + v2.y, 0.f);
    acc.z += fmaxf(xs.z + v0.z + v1.z + v2.z, 0.f);
    acc.w += fmaxf(xs.w + v0.w + v1.w + v2.w, 0.f);
  }
  *(float4*)(out + (size_t)n * H + c4) = acc;
}

__global__ __launch_bounds__(256) void gather_agg_k(const int* __restrict__ off,
    const int* __restrict__ ids, const int* __restrict__ sidx,
    const float* __restrict__ src, const float* __restrict__ base,
    float* __restrict__ out, int N) {
  int n = blockIdx.x * 8 + (threadIdx.x >> 5);
  if (n >= N) return;
  int c4 = (threadIdx.x & 31) * 4;
  float4 acc = make_float4(0.f, 0.f, 0.f, 0.f);
  if (base) acc = *(const float4*)(base + (size_t)n * H + c4);
  int p0 = off[n], p1 = off[n + 1];
  for (int p = p0; p < p1; ++p) {
    int m = ids[p];
    int sr = sidx ? sidx[m] : m;
    float4 v = *(const float4*)(src + (size_t)sr * H + c4);
    acc.x += v.x; acc.y += v.y; acc.z += v.z; acc.w += v.w;
  }
  *(float4*)(out + (size_t)n * H + c4) = acc;
}

__device__ __forceinline__ int lowb(const int* __restrict__ a, int n, int v) {
  int lo = 0, hi = n;
  while (lo < hi) { int mid = (lo + hi) >> 1; if (a[mid] < v) lo = mid + 1; else hi = mid; }
  return lo;
}

__global__ __launch_bounds__(256) void pool_mean_k(const int* __restrict__ bidx,
    const float* __restrict__ src, float* __restrict__ out, int n, int G) {
  int g = blockIdx.x * 8 + (threadIdx.x >> 5);
  if (g >= G) return;
  int c4 = (threadIdx.x & 31) * 4;
  int lo = lowb(bidx, n, g), hi = lowb(bidx, n, g + 1);
  float4 acc = make_float4(0.f, 0.f, 0.f, 0.f);
  for (int r = lo; r < hi; ++r) {
    float4 v = *(const float4*)(src + (size_t)r * H + c4);
    acc.x += v.x; acc.y += v.y; acc.z += v.z; acc.w += v.w;
  }
  float inv = 1.0f / (float)max(hi - lo, 1);
  acc.x *= inv; acc.y *= inv; acc.z *= inv; acc.w *= inv;
  *(float4*)(out + (size_t)g * H + c4) = acc;
}

// ---------------- batchnorm helpers ----------------

__global__ void bn_final_k(const float* __restrict__ ssum, const float* __restrict__ ssq,
    float* __restrict__ mu, float* __restrict__ rsig, int C, float invM) {
  int c = threadIdx.x + blockIdx.x * blockDim.x;
  if (c < C) {
    float m = ssum[c] * invM;
    float v = ssq[c] * invM - m * m;
    mu[c] = m;
    rsig[c] = rsqrtf(v + 1e-5f);
  }
}

__global__ __launch_bounds__(256) void bn_apply_relu_k(const float* __restrict__ X,
    const float* __restrict__ mu, const float* __restrict__ rsig,
    float* __restrict__ Out, int M) {
  long long t = (long long)blockIdx.x * 256 + threadIdx.x;
  if (t >= (long long)M * 32) return;
  int c4 = ((int)(t & 31)) * 4;
  float4 v = ((const float4*)X)[t];
  float4 m4 = *(const float4*)&mu[c4];
  float4 r4 = *(const float4*)&rsig[c4];
  v.x = fmaxf((v.x - m4.x) * r4.x, 0.f);
  v.y = fmaxf((v.y - m4.y) * r4.y, 0.f);
  v.z = fmaxf((v.z - m4.z) * r4.z, 0.f);
  v.w = fmaxf((v.w - m4.w) * r4.w, 0.f);
  ((float4*)Out)[t] = v;
}

// ---------------- MFMA MLP stats: pair-tiled 512-thread blocks ----------------
// waves 0-3 -> tile 2*pb, waves 4-7 -> tile 2*pb+1; W1 chunk staged once for both.

__global__ __launch_bounds__(512) void mlp_stats_mfma_k(
    const float* __restrict__ A, const short* __restrict__ w1h, const short* __restrict__ w1l,
    float* __restrict__ ssum, float* __restrict__ ssq, int M, int npairs) {
  __shared__ __align__(16) short Wch[8192], Wcl[8192];
  __shared__ float sRed[256], qRed[256];
  int tid = threadIdx.x;
  if (tid < 256) { sRed[tid] = 0.f; qRed[tid] = 0.f; }
  int w = tid >> 6, l = tid & 63, l15 = l & 15, lg = l >> 4;
  int h = w >> 2, wl = w & 3;
  float sAcc[16], qAcc[16];
#pragma unroll
  for (int nt = 0; nt < 16; ++nt) { sAcc[nt] = 0.f; qAcc[nt] = 0.f; }
  for (int pb = blockIdx.x; pb < npairs; pb += gridDim.x) {
    int tile = pb * 2 + h;
    int arow = tile * 64 + wl * 16 + l15;
    bool av = arow < M;
    bf8 ah[4], al_[4];
    load_afrags(A + (size_t)arow * 128 + lg * 8, av, 1.f, ah, al_);
    for (int ch = 0; ch < 4; ++ch) {
      __syncthreads();
      const bf8* srcH = (const bf8*)(w1h + ch * 8192);
      const bf8* srcL = (const bf8*)(w1l + ch * 8192);
      for (int it = tid; it < 1024; it += 512) {
        ((bf8*)Wch)[it] = srcH[it];
        ((bf8*)Wcl)[it] = srcL[it];
      }
      __syncthreads();
#pragma unroll
      for (int ntl = 0; ntl < 4; ++ntl) {
        f32x4v c = {0.f, 0.f, 0.f, 0.f};
#pragma unroll
        for (int ks = 0; ks < 4; ++ks) {
          bf8 bh = *(const bf8*)&Wch[(ntl * 4 + ks) * 512 + l * 8];
          bf8 bl = *(const bf8*)&Wcl[(ntl * 4 + ks) * 512 + l * 8];
          c = mfma16(al_[ks], bh, c);
          c = mfma16(ah[ks], bl, c);
          c = mfma16(ah[ks], bh, c);
        }
        int nt = ch * 4 + ntl;
        if (av) {
          sAcc[nt] += c[0] + c[1] + c[2] + c[3];
          qAcc[nt] += c[0]*c[0] + c[1]*c[1] + c[2]*c[2] + c[3]*c[3];
        }
      }
    }
  }
  __syncthreads();
#pragma unroll
  for (int nt = 0; nt < 16; ++nt) {
    float s = sAcc[nt], q = qAcc[nt];
    s += __shfl_xor(s, 16); s += __shfl_xor(s, 32);
    q += __shfl_xor(q, 16); q += __shfl_xor(q, 32);
    if (l < 16) { atomicAdd(&sRed[nt * 16 + l], s); atomicAdd(&qRed[nt * 16 + l], q); }
  }
  __syncthreads();
  if (tid < 256) { atomicAdd(&ssum[tid], sRed[tid]); atomicAdd(&ssq[tid], qRed[tid]); }
}

// NOTE: stats counted rows via av-guard; invalid tail rows contribute zeros to MFMA
// but are excluded from sums (av check above). Zero rows would otherwise bias mean.

// ---------------- MFMA fused MLP: pair-tiled 512-thread blocks ----------------

__global__ __launch_bounds__(512) void mlp_fused_mfma_k(
    float* __restrict__ A, const short* __restrict__ w1h, const short* __restrict__ w1l,
    const short* __restrict__ w2h, const short* __restrict__ w2l,
    const float* __restrict__ mu, const float* __restrict__ rsig,
    float* __restrict__ ssum, float* __restrict__ ssq, int M, int npairs) {
  __shared__ __align__(16) short Wch[8192], Wcl[8192];     // 32 KB
  __shared__ __align__(16) float h1f[2][64][132];          // 67.6 KB
  __shared__ float sRed[128], qRed[128];
  int tid = threadIdx.x;
  if (tid < 128) { sRed[tid] = 0.f; qRed[tid] = 0.f; }
  int w = tid >> 6, l = tid & 63, l15 = l & 15, lg = l >> 4;
  int h = w >> 2, wl = w & 3;
  float sAcc[8], qAcc[8];
#pragma unroll
  for (int nt = 0; nt < 8; ++nt) { sAcc[nt] = 0.f; qAcc[nt] = 0.f; }
  for (int pb = blockIdx.x; pb < npairs; pb += gridDim.x) {
    int tile = pb * 2 + h;
    int arow = tile * 64 + wl * 16 + l15;
    bool av = arow < M;
    f32x4v acc[8];
#pragma unroll
    for (int nt = 0; nt < 8; ++nt) acc[nt] = (f32x4v){0.f, 0.f, 0.f, 0.f};
    for (int kh = 0; kh < 2; ++kh) {
      {
        bf8 ah[4], al_[4];
        load_afrags(A + (size_t)arow * 128 + lg * 8, av, 1.f, ah, al_);
        for (int ch = 0; ch < 2; ++ch) {
          int cbase = kh * 8 + ch * 4;
          __syncthreads();
          const bf8* srcH = (const bf8*)(w1h + cbase * 2048);
          const bf8* srcL = (const bf8*)(w1l + cbase * 2048);
          for (int it = tid; it < 1024; it += 512) {
            ((bf8*)Wch)[it] = srcH[it];
            ((bf8*)Wcl)[it] = srcL[it];
          }
          __syncthreads();
#pragma unroll
          for (int ntl = 0; ntl < 4; ++ntl) {
            f32x4v c = {0.f, 0.f, 0.f, 0.f};
#pragma unroll
            for (int ks = 0; ks < 4; ++ks) {
              bf8 bh = *(const bf8*)&Wch[(ntl * 4 + ks) * 512 + l * 8];
              bf8 bl = *(const bf8*)&Wcl[(ntl * 4 + ks) * 512 + l * 8];
              c = mfma16(al_[ks], bh, c);
              c = mfma16(ah[ks], bl, c);
              c = mfma16(ah[ks], bh, c);
            }
            int cn = cbase + ntl;
            int cc = cn * 16 + l15;
            float mm = mu[cc], rs = rsig[cc];
#pragma unroll
            for (int r = 0; r < 4; ++r) {
              float t = fmaxf((c[r] - mm) * rs, 0.f);
              h1f[h][wl * 16 + lg * 4 + r][(cn & 7) * 16 + l15] = t;
            }
          }
        }
      }
      __syncthreads();
      bf8 a2h[4], a2l[4];
#pragma unroll
      for (int ks2 = 0; ks2 < 4; ++ks2) {
        const float* hp = &h1f[h][wl * 16 + l15][ks2 * 32 + lg * 8];
#pragma unroll
        for (int j = 0; j < 8; ++j) {
          short hh, ll; splitf(hp[j], hh, ll);
          a2h[ks2][j] = hh; a2l[ks2][j] = ll;
        }
      }
      for (int c2 = 0; c2 < 2; ++c2) {
        __syncthreads();
        for (int it = tid; it < 1024; it += 512) {
          int e = it * 8;
          int ntl = e >> 11, rem = e & 2047;
          int ks2 = rem >> 9, s = rem & 511;
          int src = ((c2 * 4 + ntl) * 8 + kh * 4 + ks2) * 512 + s;
          ((bf8*)Wch)[it] = *(const bf8*)(w2h + src);
          ((bf8*)Wcl)[it] = *(const bf8*)(w2l + src);
        }
        __syncthreads();
#pragma unroll
        for (int ntl = 0; ntl < 4; ++ntl) {
          f32x4v c = acc[c2 * 4 + ntl];
#pragma unroll
          for (int ks2 = 0; ks2 < 4; ++ks2) {
            bf8 bh = *(const bf8*)&Wch[(ntl * 4 + ks2) * 512 + l * 8];
            bf8 bl = *(const bf8*)&Wcl[(ntl * 4 + ks2) * 512 + l * 8];
            c = mfma16(a2l[ks2], bh, c);
            c = mfma16(a2h[ks2], bl, c);
            c = mfma16(a2h[ks2], bh, c);
          }
          acc[c2 * 4 + ntl] = c;
        }
      }
    }
    int base = tile * 64 + wl * 16;
#pragma unroll
    for (int nt = 0; nt < 8; ++nt) {
      int cc = nt * 16 + l15;
#pragma unroll
      for (int r = 0; r < 4; ++r) {
        int gr = base + lg * 4 + r;
        if (gr < M) {
          float vv = acc[nt][r];
          A[(size_t)gr * 128 + cc] = vv;
          sAcc[nt] += vv;
          qAcc[nt] = fmaf(vv, vv, qAcc[nt]);
        }
      }
    }
  }
  __syncthreads();
#pragma unroll
  for (int nt = 0; nt < 8; ++nt) {
    float s = sAcc[nt], q = qAcc[nt];
    s += __shfl_xor(s, 16); s += __shfl_xor(s, 32);
    q += __shfl_xor(q, 16); q += __shfl_xor(q, 32);
    if (l < 16) { atomicAdd(&sRed[nt * 16 + l], s); atomicAdd(&qRed[nt * 16 + l], q); }
  }
  __syncthreads();
  if (tid < 128) { atomicAdd(&ssum[tid], sRed[tid]); atomicAdd(&ssq[tid], qRed[tid]); }
}

// ---------------- MFMA 128x128 GEMM: Out = Out + relu((A*aux) @ W) ----------------

__global__ __launch_bounds__(256) void gemm128_mfma_k(
    const float* __restrict__ A0, const float* __restrict__ AUX,
    const short* __restrict__ wh, const short* __restrict__ wl,
    float* __restrict__ Out, int M, int ntiles) {
  __shared__ __align__(16) short Wh[16384], Wl[16384];
  int tid = threadIdx.x;
  for (int i = tid; i < 2048; i += 256) {
    ((f32x4v*)Wh)[i] = ((const f32x4v*)wh)[i];
    ((f32x4v*)Wl)[i] = ((const f32x4v*)wl)[i];
  }
  __syncthreads();
  int w = tid >> 6, l = tid & 63, l15 = l & 15, lg = l >> 4;
  for (int tb = blockIdx.x; tb < ntiles; tb += gridDim.x) {
    int arow = tb * 64 + w * 16 + l15;
    bool av = arow < M;
    float sc = av ? AUX[arow] : 0.f;
    bf8 ah[4], al_[4];
    load_afrags(A0 + (size_t)arow * 128 + lg * 8, av, sc, ah, al_);
    int base = tb * 64 + w * 16;
#pragma unroll
    for (int nt = 0; nt < 8; ++nt) {
      f32x4v c = {0.f, 0.f, 0.f, 0.f};
#pragma unroll
      for (int ks = 0; ks < 4; ++ks) {
        bf8 bh = *(const bf8*)&Wh[(nt * 4 + ks) * 512 + l * 8];
        bf8 bl = *(const bf8*)&Wl[(nt * 4 + ks) * 512 + l * 8];
        c = mfma16(al_[ks], bh, c);
        c = mfma16(ah[ks], bl, c);
        c = mfma16(ah[ks], bh, c);
      }
#pragma unroll
      for (int r = 0; r < 4; ++r) {
        int gr = base + lg * 4 + r;
        if (gr < M) {
          size_t o = (size_t)gr * 128 + nt * 16 + l15;
          Out[o] = Out[o] + fmaxf(c[r], 0.f);
        }
      }
    }
  }
}

// ---------------- f32 GEMM for readout ----------------
template<int EPI>
__global__ __launch_bounds__(256) void gemm_k(
    const float* __restrict__ A0, const float* __restrict__ W,
    float* __restrict__ Out, int M) {
  __shared__ __align__(16) float Ash[64][64];
  int tid = threadIdx.x;
  int tc = tid & 63, tr = tid >> 6;
  int row0 = blockIdx.x * 64;
  float acc[16][2];
#pragma unroll
  for (int i = 0; i < 16; ++i) { acc[i][0] = 0.f; acc[i][1] = 0.f; }
  for (int k0 = 0; k0 < 128; k0 += 64) {
#pragma unroll
    for (int it = 0; it < 4; ++it) {
      int fidx = tid + it * 256;
      int r = fidx >> 4, c4 = (fidx & 15) << 2;
      int gr = row0 + r;
      float4 v = make_float4(0.f, 0.f, 0.f, 0.f);
      if (gr < M) v = *(const float4*)(A0 + (size_t)gr * 128 + k0 + c4);
      *(float4*)&Ash[r][c4] = v;
    }
    __syncthreads();
    const float* Wp = W + (size_t)k0 * 128 + tc;
    for (int kk = 0; kk < 64; kk += 4) {
      float w[4][2];
#pragma unroll
      for (int kj = 0; kj < 4; ++kj)
#pragma unroll
        for (int j = 0; j < 2; ++j) w[kj][j] = Wp[(size_t)(kk + kj) * 128 + j * 64];
#pragma unroll
      for (int i = 0; i < 16; ++i) {
        float4 a = *(const float4*)&Ash[tr * 16 + i][kk];
#pragma unroll
        for (int j = 0; j < 2; ++j) {
          acc[i][j] = fmaf(a.x, w[0][j], acc[i][j]);
          acc[i][j] = fmaf(a.y, w[1][j], acc[i][j]);
          acc[i][j] = fmaf(a.z, w[2][j], acc[i][j]);
          acc[i][j] = fmaf(a.w, w[3][j], acc[i][j]);
        }
      }
    }
    __syncthreads();
  }
#pragma unroll
  for (int i = 0; i < 16; ++i) {
    int gr = row0 + tr * 16 + i;
    if (gr < M) {
#pragma unroll
      for (int j = 0; j < 2; ++j) {
        size_t o = (size_t)gr * 128 + tc + j * 64;
        float v = acc[i][j];
        if (EPI == 0) Out[o] = v;
        else Out[o] = fmaxf(Out[o] + v, 0.f);
      }
    }
  }
}

// ---------------- host ----------------

static inline int cdivll(long long a, long long b) { return (int)((a + b - 1) / b); }

extern "C" void kernel_launch(void* const* d_in, const int* in_sizes, int n_in,
                              void* d_out, int out_size, void* d_ws, size_t ws_size,
                              hipStream_t stream) {
  const int* node_feat  = (const int*)d_in[0];
  const int* edge_index = (const int*)d_in[1];
  const int* edge_feat  = (const int*)d_in[2];
  const int* batch      = (const int*)d_in[3];
  const int* map_row    = (const int*)d_in[4];
  const int* map_col    = (const int*)d_in[5];
  const int* rg_ei      = (const int*)d_in[6];
  const int* rg_feat    = (const int*)d_in[7];
  const int* tree_batch = (const int*)d_in[8];
  const float* atom_emb   = (const float*)d_in[10];
  const float* bond_emb   = (const float*)d_in[11];
  const float* rg_emb     = (const float*)d_in[12];
  const float* atom_W1    = (const float*)d_in[13];
  const float* atom_W2    = (const float*)d_in[14];
  const float* rg_W1      = (const float*)d_in[15];
  const float* rg_W2      = (const float*)d_in[16];
  const float* raw2rg_W   = (const float*)d_in[17];
  const float* rg2raw_W   = (const float*)d_in[18];
  const float* atom_lin_W = (const float*)d_in[19];
  const float* rg_lin_W   = (const float*)d_in[20];
  const float* lin_W      = (const float*)d_in[21];

  const int N   = in_sizes[0] / 9;
  const int E   = in_sizes[1] / 2;
  const int M   = in_sizes[4];
  const int NRG = in_sizes[7];
  const int ERG = in_sizes[6] / 2;
  const int G   = out_size / H;
  if (N <= 0 || G <= 0) return;

  const size_t NH = (size_t)N * H, RH = (size_t)NRG * H, GH = (size_t)G * H;
  const int cmax = max(N, NRG);

  const size_t nfloat = 2 * NH + RH + (size_t)NRG + (size_t)N + 1024;
  const size_t nint = (size_t)(N + 1) * 2 + (size_t)(NRG + 1) * 2
                    + (size_t)E + 2 * (size_t)M + (size_t)ERG + (size_t)cmax + 1024;
  const size_t nshort = 3 * (4 * 32768 + 2 * 16384);
  const size_t need = nfloat * 4 + nint * 4 + nshort * 2 + 256;
  if (ws_size < need) return;

  float* ws = (float*)d_ws;
  size_t off = 0;
  auto alloc = [&](size_t n) { float* p = ws + off; off += n; return p; };
  float* x       = alloc(NH);
  float* abuf    = alloc(NH);
  float* rg      = alloc(RH);
  float* inv_col = alloc((size_t)NRG);
  float* inv_row = alloc((size_t)N);
  float* ssum = alloc(256);
  float* ssq  = alloc(256);
  float* mu   = alloc(256);
  float* rsig = alloc(256);

  int* ip = (int*)(ws + off);
  size_t ioff = 0;
  auto ialloc = [&](size_t n) { int* p = ip + ioff; ioff += n; return p; };
  int* off_dst = ialloc((size_t)N + 1);
  int* off_col = ialloc((size_t)NRG + 1);
  int* off_row = ialloc((size_t)N + 1);
  int* off_rg  = ialloc((size_t)NRG + 1);
  int* ids_dst = ialloc((size_t)E);
  int* ids_col = ialloc((size_t)M);
  int* ids_row = ialloc((size_t)M);
  int* ids_rg  = ialloc((size_t)ERG);
  int* tmp_cnt = ialloc((size_t)cmax);
  int* bsum    = ialloc(1024);

  short* sp = (short*)(ip + ioff);
  size_t soff = 0;
  auto salloc = [&](size_t n) { short* p = sp + soff; soff += n; return p; };
  short* paW1h = salloc(3 * 32768); short* paW1l = salloc(3 * 32768);
  short* paW2h = salloc(3 * 32768); short* paW2l = salloc(3 * 32768);
  short* prW1h = salloc(3 * 32768); short* prW1l = salloc(3 * 32768);
  short* prW2h = salloc(3 * 32768); short* prW2l = salloc(3 * 32768);
  short* p2gh  = salloc(3 * 16384); short* p2gl  = salloc(3 * 16384);
  short* pg2h  = salloc(3 * 16384); short* pg2l  = salloc(3 * 16384);

  const int ta = (N + 63) >> 6, trg = (NRG + 63) >> 6;
  const int pa = (ta + 1) >> 1, prg = (trg + 1) >> 1;
  const int ga2 = pa < 512 ? pa : 512, grg2 = prg < 512 ? prg : 512;
  const int ga = ta < 512 ? ta : 512, grg = trg < 512 ? trg : 512;

  // ---- pack weights ----
  pack_w_k<<<dim3(128, 3), 256, 0, stream>>>(atom_W1, paW1h, paW1l, 128, 256);
  pack_w_k<<<dim3(128, 3), 256, 0, stream>>>(atom_W2, paW2h, paW2l, 256, 128);
  pack_w_k<<<dim3(128, 3), 256, 0, stream>>>(rg_W1, prW1h, prW1l, 128, 256);
  pack_w_k<<<dim3(128, 3), 256, 0, stream>>>(rg_W2, prW2h, prW2l, 256, 128);
  pack_w_k<<<dim3(64, 3), 256, 0, stream>>>(raw2rg_W, p2gh, p2gl, 128, 128);
  pack_w_k<<<dim3(64, 3), 256, 0, stream>>>(rg2raw_W, pg2h, pg2l, 128, 128);

  // ---- CSR builds ----
  auto build_csr = [&](const int* idx, int nelem, int nrows, int* offs, int* ids,
                       float* inv) {
    hipMemsetAsync(tmp_cnt, 0, (size_t)nrows * 4, stream);
    icount_k<<<cdivll(nelem, 256), 256, 0, stream>>>(idx, tmp_cnt, nelem);
    if (inv) inv_from_int_k<<<cdivll(nrows, 256), 256, 0, stream>>>(tmp_cnt, inv, nrows);
    int nblk = cdivll(nrows, 1024);
    seg_blocksum_k<<<nblk, 256, 0, stream>>>(tmp_cnt, bsum, nrows);
    seg_scan_k<<<nblk, 256, 0, stream>>>(tmp_cnt, bsum, offs, tmp_cnt, nrows, nblk);
    seg_fill_k<<<cdivll(nelem, 256), 256, 0, stream>>>(idx, tmp_cnt, ids, nelem);
  };
  build_csr(edge_index + E, E, N, off_dst, ids_dst, nullptr);
  build_csr(map_col, M, NRG, off_col, ids_col, inv_col);
  build_csr(map_row, M, N, off_row, ids_row, inv_row);
  build_csr(rg_ei + ERG, ERG, NRG, off_rg, ids_rg, nullptr);

  // ---- encoders ----
  atom_encode_k<<<cdivll(NH, 256), 256, 0, stream>>>(node_feat, atom_emb, x, N);
  rg_init_k<<<cdivll(RH, 256), 256, 0, stream>>>(rg_feat, rg_emb, rg, NRG);

  for (int i = 0; i < 3; ++i) {
    // --- GINE: abuf = x + sum relu(x[src]+e) ---
    gine_agg_k<<<cdivll(N, 8), 256, 0, stream>>>(off_dst, ids_dst, edge_index, edge_feat,
        bond_emb + (size_t)i * 3 * 100 * H, x, abuf, N);
    // --- atom MLP (MFMA, pair-tiled) ---
    hipMemsetAsync(ssum, 0, 512 * 4, stream);
    mlp_stats_mfma_k<<<ga2, 512, 0, stream>>>(abuf, paW1h + i * 32768, paW1l + i * 32768, ssum, ssq, N, pa);
    bn_final_k<<<1, 256, 0, stream>>>(ssum, ssq, mu, rsig, 256, 1.0f / N);
    hipMemsetAsync(ssum, 0, 512 * 4, stream);
    mlp_fused_mfma_k<<<ga2, 512, 0, stream>>>(abuf, paW1h + i * 32768, paW1l + i * 32768,
        paW2h + i * 32768, paW2l + i * 32768, mu, rsig, ssum, ssq, N, pa);
    bn_final_k<<<1, 256, 0, stream>>>(ssum, ssq, mu, rsig, 128, 1.0f / N);
    bn_apply_relu_k<<<cdivll((long long)N * 32, 256), 256, 0, stream>>>(abuf, mu, rsig, x, N);

    // --- raw -> rg ---
    gather_agg_k<<<cdivll(NRG, 8), 256, 0, stream>>>(off_col, ids_col, map_row, x, nullptr, abuf, NRG);
    gemm128_mfma_k<<<grg, 256, 0, stream>>>(abuf, inv_col, p2gh + i * 16384, p2gl + i * 16384,
        rg, NRG, trg);

    // --- rg GIN ---
    gather_agg_k<<<cdivll(NRG, 8), 256, 0, stream>>>(off_rg, ids_rg, rg_ei, rg, rg, abuf, NRG);
    hipMemsetAsync(ssum, 0, 512 * 4, stream);
    mlp_stats_mfma_k<<<grg2, 512, 0, stream>>>(abuf, prW1h + i * 32768, prW1l + i * 32768, ssum, ssq, NRG, prg);
    bn_final_k<<<1, 256, 0, stream>>>(ssum, ssq, mu, rsig, 256, 1.0f / NRG);
    hipMemsetAsync(ssum, 0, 512 * 4, stream);
    mlp_fused_mfma_k<<<grg2, 512, 0, stream>>>(abuf, prW1h + i * 32768, prW1l + i * 32768,
        prW2h + i * 32768, prW2l + i * 32768, mu, rsig, ssum, ssq, NRG, prg);
    bn_final_k<<<1, 256, 0, stream>>>(ssum, ssq, mu, rsig, 128, 1.0f / NRG);
    bn_apply_relu_k<<<cdivll((long long)NRG * 32, 256), 256, 0, stream>>>(abuf, mu, rsig, rg, NRG);

    // --- rg -> raw ---
    gather_agg_k<<<cdivll(N, 8), 256, 0, stream>>>(off_row, ids_row, map_col, rg, nullptr, abuf, N);
    gemm128_mfma_k<<<ga, 256, 0, stream>>>(abuf, inv_row, pg2h + i * 16384, pg2l + i * 16384,
        x, N, ta);
  }

  // ---- readout ----
  float* xg  = abuf;
  float* rgg = abuf + GH;
  float* P   = abuf + 2 * GH;
  pool_mean_k<<<cdivll(G, 8), 256, 0, stream>>>(batch, x, xg, N, G);
  pool_mean_k<<<cdivll(G, 8), 256, 0, stream>>>(tree_batch, rg, rgg, NRG, G);
  gemm_k<0><<<cdivll(G, 64), 256, 0, stream>>>(xg, atom_lin_W, P, G);
  gemm_k<2><<<cdivll(G, 64), 256, 0, stream>>>(rgg, rg_lin_W, P, G);
  gemm_k<0><<<cdivll(G, 64), 256, 0, stream>>>(P, lin_W, (float*)d_out, G);
}